// Round 17
// baseline (228.176 us; speedup 1.0000x reference)
//
#include <hip/hip_runtime.h>
#include <hip/hip_bf16.h>

#define BATCH 128
#define CDIV(a, b) (((a) + (b) - 1) / (b))

typedef __attribute__((ext_vector_type(8))) short short8;
typedef __attribute__((ext_vector_type(4))) float f32x4;

// compile-time unroll helpers
template <int V> struct ic { static constexpr int value = V; };
template <int... I> struct iseq {};
template <int N, int... I> struct mkseq : mkseq<N - 1, N - 1, I...> {};
template <int... I> struct mkseq<0, I...> { using type = iseq<I...>; };
template <class F, int... I>
__device__ __forceinline__ void unroll_all(F&& f, iseq<I...>) { (f(ic<I>{}), ...); }

// async global->LDS 16B: LDS dest = wave-uniform base + lane*16; global source per-lane
__device__ __forceinline__ void gload_lds16(const void* g, void* l) {
    __builtin_amdgcn_global_load_lds(
        (const __attribute__((address_space(1))) void*)g,
        (__attribute__((address_space(3))) void*)l, 16, 0, 0);
}

// 16B-unit swizzle sigma(u) = u ^ ((u>>2)&7) (bank spread for stride-4-unit frag reads)
__device__ __forceinline__ int sig_u(int u) { return u ^ ((u >> 2) & 7); }
__device__ __forceinline__ int inv_sig_u(int x) {
    int r0 = ((x >> 2) ^ (x >> 4)) & 1;
    int r1 = (x >> 3) & 1;
    int r2 = (x >> 4) & 1;
    return x ^ (r0 | (r1 << 1) | (r2 << 2));
}

// ---------------- zero fill (f32) ----------------
__global__ void fill0_f32(float* __restrict__ p, int n) {
    int i = blockIdx.x * blockDim.x + threadIdx.x;
    if (i < n) p[i] = 0.0f;
}

// ---------------- decode: scatter A0 -> padded NHWC f32 [B][34][34][4] ----------------
__global__ void decode_kernel(const float* __restrict__ y, const int* __restrict__ p,
                              const float* __restrict__ s, float* __restrict__ x) {
    const int n = 3073;
    int idx = blockIdx.x * blockDim.x + threadIdx.x;
    if (idx >= BATCH * n) return;
    int i = idx % n, b = idx / n;
    int pi = p[i];
    if (pi >= 3072) return;
    float v = y[(size_t)b * n + i] / s[i];
    int c = pi >> 10; int r = pi & 1023; int h = r >> 5; int w = r & 31;
    x[((size_t)(b * 34 + h + 1) * 34 + (w + 1)) * 4 + c] = v;
}

// ---------------- fused halo zero (up to 4 padded bf16 NHWC buffers) ----------------
struct HaloDesc { __hip_bfloat16* p; int Hp, Wp, C; };
struct Halo4 { HaloDesc d[4]; int cum[5]; int n; };

__global__ void halo_zero_multi(Halo4 h) {
    int idx = blockIdx.x * 256 + threadIdx.x;
    if (idx >= h.cum[h.n]) return;
    int seg = 0;
    while (idx >= h.cum[seg + 1]) ++seg;
    int local = idx - h.cum[seg];
    HaloDesc d = h.d[seg];
    int perB = (2 * d.Wp + 2 * (d.Hp - 2)) * d.C / 8;
    int b = local / perB;
    int r = (local % perB) * 8;
    int WpC = d.Wp * d.C;
    long addr;
    if (r < WpC) {
        addr = (long)(b * d.Hp) * WpC + r;
    } else if (r < 2 * WpC) {
        addr = (long)(b * d.Hp + d.Hp - 1) * WpC + (r - WpC);
    } else {
        int r3 = r - 2 * WpC;
        int sideN = (d.Hp - 2) * d.C;
        int side = r3 / sideN;
        int r4 = r3 % sideN;
        int row = 1 + r4 / d.C, c = r4 % d.C;
        addr = ((long)(b * d.Hp + row) * d.Wp + (side ? d.Wp - 1 : 0)) * d.C + c;
    }
    *(uint4*)((char*)d.p + addr * 2) = uint4{0, 0, 0, 0};
}

// ------ fused weight transform: OIHW f32 -> [pos*KS+kk][CoutPad][32] bf16 (k-chunked) ---
struct WtSeg { const float* src; __hip_bfloat16* dst; int Cout, Cin, KK, CoutPad; };
struct Wt8 { WtSeg s[8]; int cum[9]; };

__global__ void wt_transform_multi(Wt8 w) {
    int idx = blockIdx.x * 256 + threadIdx.x;
    if (idx >= w.cum[8]) return;
    int seg = 0;
    while (idx >= w.cum[seg + 1]) ++seg;
    int local = idx - w.cum[seg];
    WtSeg sg = w.s[seg];
    int c2 = local % 32; int t = local / 32;
    int co = t % sg.CoutPad; int t2 = t / sg.CoutPad;   // t2 = pos*KS + kk
    int KS = sg.Cin / 32;
    int kk = t2 % KS; int pos = t2 / KS;
    int cin = kk * 32 + c2;
    float v = (co < sg.Cout) ? sg.src[((size_t)co * sg.Cin + cin) * sg.KK + pos] : 0.0f;
    sg.dst[local] = __float2bfloat16(v);
}

// ---------------- conv1: 3->96 @32x32, fp32, 4 threads/pixel, packed stores ------------
__global__ __launch_bounds__(256) void conv1_kernel(
    const float* __restrict__ in, const float* __restrict__ w,
    const float* __restrict__ bias, __hip_bfloat16* __restrict__ out) {
    __shared__ float ws[96 * 27];
    __shared__ float bs[96];
    for (int i = threadIdx.x; i < 96 * 27; i += 256) ws[i] = w[i];
    if (threadIdx.x < 96) bs[threadIdx.x] = bias[threadIdx.x];
    __syncthreads();
    int idx = blockIdx.x * 256 + threadIdx.x;
    int q = idx & 3; int pix = idx >> 2;
    int b = pix >> 10, r = pix & 1023, oh = r >> 5, ow = r & 31;
    const float* ib = in + ((size_t)(b * 34 + oh) * 34 + ow) * 4;
    float patch[9][3];
#pragma unroll
    for (int ph = 0; ph < 3; ++ph)
#pragma unroll
        for (int pw = 0; pw < 3; ++pw) {
            float4 v = *(const float4*)(ib + ((size_t)ph * 34 + pw) * 4);
            patch[ph * 3 + pw][0] = v.x; patch[ph * 3 + pw][1] = v.y; patch[ph * 3 + pw][2] = v.z;
        }
    const int c0 = q * 24;
    float acc[24];
#pragma unroll
    for (int j = 0; j < 24; ++j) acc[j] = bs[c0 + j];
    for (int j = 0; j < 24; ++j) {
        const float* wc = &ws[(c0 + j) * 27];
#pragma unroll
        for (int ci = 0; ci < 3; ++ci)
#pragma unroll
            for (int pos = 0; pos < 9; ++pos)
                acc[j] = fmaf(patch[pos][ci], wc[ci * 9 + pos], acc[j]);
    }
    __hip_bfloat16* ob = out + ((size_t)(b * 34 + oh + 1) * 34 + ow + 1) * 96 + c0;
#pragma unroll
    for (int g = 0; g < 3; ++g) {
        union { uint4 u; unsigned short s[8]; } pk;
#pragma unroll
        for (int e = 0; e < 8; ++e) {
            __hip_bfloat16 hv = __float2bfloat16(fmaxf(acc[g * 8 + e], 0.0f));
            pk.s[e] = *(unsigned short*)&hv;
        }
        *(uint4*)(ob + g * 8) = pk.u;
    }
}

// ======== conv_2ph: shared LDS chunk ring + counted vmcnt + RAW barrier, WMxWN waves ====
// LA=1/DEPTH=3 variant: minimum race-free ring (DEPTH >= LA+2). Shallow per-wave
// pipeline; latency hidden by TLP (24-36KB LDS -> 3-4 blocks/CU). Per K-step s:
// stage chunk s+1, vmcnt(C*LPW) (chunk s landed), raw barrier, swizzled frag reads, MFMA.
template <int CIN, int COUT, int HIN, int WIN, int STRIDE, int R,
          int WM, int WN, int MT, int NTW, int LA, int DEPTH, int THREADS, int MINW>
__global__ __launch_bounds__(THREADS, MINW) void conv_2ph(
    const __hip_bfloat16* __restrict__ in,   // [B][HIN+2][WIN+2][CIN]
    const __hip_bfloat16* __restrict__ wt,   // [(2R+1)^2*KS][COUT][32]
    const float* __restrict__ bias,
    __hip_bfloat16* __restrict__ out) {      // [B][HOUT+2][WOUT+2][COUT]
    constexpr int HOUT = HIN / STRIDE, WOUT = WIN / STRIDE;
    constexpr int Hp = HIN + 2, Wp = WIN + 2;
    constexpr int Hpo = HOUT + 2, Wpo = WOUT + 2;
    constexpr int D = 2 * R + 1;
    constexpr int KS = CIN / 32;
    constexpr int NSTEP = D * D * KS;
    constexpr int WAVES = THREADS / 64;
    static_assert(WAVES == WM * WN, "wave grid");
    static_assert(DEPTH >= LA + 2, "race-free ring requires DEPTH >= LA+2");
    constexpr int BMPIX = WM * MT * 16;
    static_assert(WN * NTW * 16 == COUT, "N covers COUT");
    constexpr int AUN = BMPIX * 4;           // A 16B-units per chunk
    constexpr int BUN = COUT * 4;            // B 16B-units per chunk
    constexpr int CUN = AUN + BUN;
    constexpr int LPW = CDIV(CUN, 64 * WAVES);
    constexpr int CUN_ALLOC = LPW * 64 * WAVES;   // incl. scratch tail for dummy loads

    __shared__ short8 lds[DEPTH * CUN_ALLOC];

    int wid = threadIdx.x >> 6;
    int lane = threadIdx.x & 63;
    int col = lane & 15, kgrp = lane >> 4;
    int wm = wid / WN, wn = wid % WN;
    int n0 = wn * (NTW * 16);
    int mBase = wm * (MT * 16);

    // ---- per-lane stage descriptors (source pre-inverse-swizzled) ----
    const __hip_bfloat16* aSrc[LPW];
    int bOff[LPW];
    bool isA[LPW];
#pragma unroll
    for (int i = 0; i < LPW; ++i) {
        int x = (wid * LPW + i) * 64 + lane;     // LDS unit within (padded) chunk
        if (x < AUN) {
            isA[i] = true;
            int v = inv_sig_u(x);
            int p = v >> 2, q = v & 3;
            int gp = blockIdx.x * BMPIX + p;
            int b = gp / (HOUT * WOUT);
            int r = gp % (HOUT * WOUT);
            int oh = r / WOUT, ow = r % WOUT;
            aSrc[i] = in + ((size_t)(b * Hp + oh * STRIDE + 1 - R) * Wp
                            + ow * STRIDE + 1 - R) * CIN + q * 8;
            bOff[i] = 0;
        } else {
            isA[i] = false;
            // units in [AUN, CUN): real B; units >= CUN: dummy (read chunk start)
            bOff[i] = (x < CUN) ? inv_sig_u(x - AUN) * 8 : 0;
            aSrc[i] = in;
        }
    }
    // ---- frag read offsets (swizzled, within chunk) ----
    int aRd[MT], bRd[NTW];
#pragma unroll
    for (int mt = 0; mt < MT; ++mt)
        aRd[mt] = sig_u((mBase + mt * 16 + col) * 4 + kgrp);
#pragma unroll
    for (int nt = 0; nt < NTW; ++nt)
        bRd[nt] = AUN + sig_u((n0 + nt * 16 + col) * 4 + kgrp);

    auto stepAoff = [](int s) {
        int pos = s / KS, kk = s - (s / KS) * KS;
        return ((pos / D) * Wp + (pos % D)) * CIN + kk * 32;
    };
    auto stage = [&](int s) {
        int slot = s % DEPTH;
        int aoff = stepAoff(s);
        const __hip_bfloat16* wchunk = wt + (size_t)s * (COUT * 32);
#pragma unroll
        for (int i = 0; i < LPW; ++i) {
            const __hip_bfloat16* src = isA[i] ? (aSrc[i] + aoff) : (wchunk + bOff[i]);
            gload_lds16(src, &lds[slot * CUN_ALLOC + (wid * LPW + i) * 64]);
        }
    };

    f32x4 acc[MT][NTW] = {};
#pragma unroll
    for (int c = 0; c < LA; ++c)
        if (c < NSTEP) stage(c);

    unroll_all([&](auto sc) {
        constexpr int s = decltype(sc)::value;
        if constexpr (s + LA < NSTEP) stage(s + LA);
        constexpr int REM = NSTEP - 1 - s;
        constexpr int C = REM < 0 ? 0 : (REM < LA ? REM : LA);
        asm volatile("s_waitcnt vmcnt(%0)" :: "i"(C * LPW) : "memory");
        __builtin_amdgcn_s_barrier();            // raw rendezvous, no drain
        __builtin_amdgcn_sched_barrier(0);
        constexpr int slot = s % DEPTH;
        short8 af[MT], bfr[NTW];
#pragma unroll
        for (int mt = 0; mt < MT; ++mt) af[mt] = lds[slot * CUN_ALLOC + aRd[mt]];
#pragma unroll
        for (int nt = 0; nt < NTW; ++nt) bfr[nt] = lds[slot * CUN_ALLOC + bRd[nt]];
#pragma unroll
        for (int nt = 0; nt < NTW; ++nt)
#pragma unroll
            for (int mt = 0; mt < MT; ++mt)
                acc[mt][nt] = __builtin_amdgcn_mfma_f32_16x16x32_bf16(
                    af[mt], bfr[nt], acc[mt][nt], 0, 0, 0);
    }, typename mkseq<NSTEP>::type{});

    // epilogue: bias + relu + bf16 store into padded NHWC
#pragma unroll
    for (int mt = 0; mt < MT; ++mt) {
#pragma unroll
        for (int nt = 0; nt < NTW; ++nt) {
            int cout = n0 + nt * 16 + col;
            float bv = bias[cout];
#pragma unroll
            for (int rg = 0; rg < 4; ++rg) {
                int p = mBase + mt * 16 + kgrp * 4 + rg;
                int gp = blockIdx.x * BMPIX + p;
                int b = gp / (HOUT * WOUT);
                int r = gp % (HOUT * WOUT);
                int oh = r / WOUT, ow = r % WOUT;
                float v = fmaxf(acc[mt][nt][rg] + bv, 0.0f);
                out[((size_t)(b * Hpo + oh + 1) * Wpo + ow + 1) * COUT + cout] =
                    __float2bfloat16(v);
            }
        }
    }
}

// ---------------- conv9: 1x1 192->10 (pad16), relu, fp32 NCHW-flat out [B][640] --------
__global__ __launch_bounds__(256) void conv9_kernel(
    const __hip_bfloat16* __restrict__ in, const __hip_bfloat16* __restrict__ wt,
    const float* __restrict__ bias, float* __restrict__ out) {
    int wid = threadIdx.x >> 6;
    int lane = threadIdx.x & 63;
    int wave = blockIdx.x * 4 + wid;
    int m0 = wave * 16;
    int col = lane & 15;
    int kgrp = lane >> 4;
    int m = m0 + col;
    int b = m >> 6; int r = m & 63; int oh = r >> 3; int ow = r & 7;
    const __hip_bfloat16* abase = in + ((size_t)(b * 10 + oh + 1) * 10 + ow + 1) * 192 + kgrp * 8;
    f32x4 acc = {};
#pragma unroll
    for (int kk = 0; kk < 6; ++kk) {
        short8 bfr = *reinterpret_cast<const short8*>(wt + ((size_t)kk * 16 + col) * 32 + kgrp * 8);
        short8 a = *reinterpret_cast<const short8*>(abase + kk * 32);
        acc = __builtin_amdgcn_mfma_f32_16x16x32_bf16(a, bfr, acc, 0, 0, 0);
    }
    if (col < 10) {
        float bv = bias[col];
#pragma unroll
        for (int rg = 0; rg < 4; ++rg) {
            int m2 = m0 + kgrp * 4 + rg;
            int b2 = m2 >> 6; int r2 = m2 & 63;
            out[(size_t)b2 * 640 + col * 64 + r2] = fmaxf(acc[rg] + bv, 0.0f);
        }
    }
}

// ---------------- fused head: fc1(640->100)+relu, fc2(100->10), encode -----------------
__global__ __launch_bounds__(128) void head_kernel(
    const float* __restrict__ act9, const float* __restrict__ fw1, const float* __restrict__ fb1,
    const float* __restrict__ fw2, const float* __restrict__ fb2,
    const int* __restrict__ p11, const float* __restrict__ s11, float* __restrict__ out) {
    __shared__ float x[640];
    __shared__ float h[100];
    __shared__ float o[10];
    int b = blockIdx.x, t = threadIdx.x;
    for (int i = t; i < 160; i += 128)
        ((float4*)x)[i] = ((const float4*)(act9 + (size_t)b * 640))[i];
    __syncthreads();
    if (t < 100) {
        float acc = fb1[t];
        const float4* wr = (const float4*)(fw1 + (size_t)t * 640);
        const float4* xv = (const float4*)x;
#pragma unroll 4
        for (int i = 0; i < 160; ++i) {
            float4 wv = wr[i], qv = xv[i];
            acc = fmaf(wv.x, qv.x, acc); acc = fmaf(wv.y, qv.y, acc);
            acc = fmaf(wv.z, qv.z, acc); acc = fmaf(wv.w, qv.w, acc);
        }
        h[t] = fmaxf(acc, 0.0f);
    }
    __syncthreads();
    if (t < 10) {
        float acc = fb2[t];
        for (int i = 0; i < 100; ++i) acc = fmaf(h[i], fw2[t * 100 + i], acc);
        o[t] = acc;
    }
    __syncthreads();
    if (t < 11) {
        int pi = p11[t];
        out[(size_t)b * 11 + t] = s11[t] * (pi == 10 ? 1.0f : o[pi]);
    }
}

extern "C" void kernel_launch(void* const* d_in, const int* in_sizes, int n_in,
                              void* d_out, int out_size, void* d_ws, size_t ws_size,
                              hipStream_t stream) {
    const int*   p0  = (const int*)  d_in[0];
    const float* s0  = (const float*)d_in[1];
    const int*   p11 = (const int*)  d_in[26];
    const float* s11 = (const float*)d_in[27];
    const float* w1 = (const float*)d_in[28]; const float* b1 = (const float*)d_in[29];
    const float* w2 = (const float*)d_in[30]; const float* b2 = (const float*)d_in[31];
    const float* w3 = (const float*)d_in[32]; const float* b3 = (const float*)d_in[33];
    const float* w4 = (const float*)d_in[34]; const float* b4 = (const float*)d_in[35];
    const float* w5 = (const float*)d_in[36]; const float* b5 = (const float*)d_in[37];
    const float* w6 = (const float*)d_in[38]; const float* b6 = (const float*)d_in[39];
    const float* w7 = (const float*)d_in[40]; const float* b7 = (const float*)d_in[41];
    const float* w8 = (const float*)d_in[42]; const float* b8 = (const float*)d_in[43];
    const float* w9 = (const float*)d_in[44]; const float* b9 = (const float*)d_in[45];
    const float* fw1 = (const float*)d_in[46]; const float* fb1 = (const float*)d_in[47];
    const float* fw2 = (const float*)d_in[48]; const float* fb2 = (const float*)d_in[49];
    const float* A0 = (const float*)d_in[50];
    float* out = (float*)d_out;

    // ---- workspace carve-up (256B aligned) ----
    size_t off = 0;
    auto alloc = [&](size_t bytes) {
        void* p = (char*)d_ws + off;
        off += (bytes + 255) & ~(size_t)255;
        return p;
    };
    const size_t SZ_3434_96  = (size_t)BATCH * 34 * 34 * 96 * 2;
    const size_t SZ_1818_96  = (size_t)BATCH * 18 * 18 * 96 * 2;
    const size_t SZ_1818_192 = (size_t)BATCH * 18 * 18 * 192 * 2;

    float* dec = (float*)alloc((size_t)BATCH * 34 * 34 * 4 * 4);
    __hip_bfloat16* regA = (__hip_bfloat16*)alloc(SZ_3434_96);   // act1; act5 [18,18,192]
    __hip_bfloat16* regB = (__hip_bfloat16*)alloc(SZ_3434_96);   // act2; act8 [10,10,192]
    __hip_bfloat16* regC = (__hip_bfloat16*)alloc(SZ_1818_96);   // act3; act6 [10,10,192]
    __hip_bfloat16* regD = (__hip_bfloat16*)alloc(SZ_1818_192);  // act4; act7 [10,10,192]
    __hip_bfloat16* wt2 = (__hip_bfloat16*)alloc((size_t)9 * 96 * 96 * 2);
    __hip_bfloat16* wt3 = (__hip_bfloat16*)alloc((size_t)9 * 96 * 96 * 2);
    __hip_bfloat16* wt4 = (__hip_bfloat16*)alloc((size_t)9 * 192 * 96 * 2);
    __hip_bfloat16* wt5 = (__hip_bfloat16*)alloc((size_t)9 * 192 * 192 * 2);
    __hip_bfloat16* wt6 = (__hip_bfloat16*)alloc((size_t)9 * 192 * 192 * 2);
    __hip_bfloat16* wt7 = (__hip_bfloat16*)alloc((size_t)9 * 192 * 192 * 2);
    __hip_bfloat16* wt8 = (__hip_bfloat16*)alloc((size_t)1 * 192 * 192 * 2);
    __hip_bfloat16* wt9 = (__hip_bfloat16*)alloc((size_t)16 * 192 * 2);
    float* act9 = (float*)alloc((size_t)BATCH * 640 * 4);

    const int TPB = 256;

    // decode input
    int decN = BATCH * 34 * 34 * 4;
    fill0_f32<<<CDIV(decN, TPB), TPB, 0, stream>>>(dec, decN);
    decode_kernel<<<CDIV(BATCH * 3073, TPB), TPB, 0, stream>>>(A0, p0, s0, dec);

    // fused weight transform (k-chunk-contiguous layout)
    Wt8 wts;
    wts.s[0] = {w2, wt2, 96, 96, 9, 96};
    wts.s[1] = {w3, wt3, 96, 96, 9, 96};
    wts.s[2] = {w4, wt4, 192, 96, 9, 192};
    wts.s[3] = {w5, wt5, 192, 192, 9, 192};
    wts.s[4] = {w6, wt6, 192, 192, 9, 192};
    wts.s[5] = {w7, wt7, 192, 192, 9, 192};
    wts.s[6] = {w8, wt8, 192, 192, 1, 192};
    wts.s[7] = {w9, wt9, 10, 192, 1, 16};
    wts.cum[0] = 0;
    for (int i = 0; i < 8; ++i)
        wts.cum[i + 1] = wts.cum[i] + wts.s[i].KK * wts.s[i].CoutPad * wts.s[i].Cin;
    wt_transform_multi<<<CDIV(wts.cum[8], TPB), TPB, 0, stream>>>(wts);

    // fused halo zero: act1, act2, act3, act4
    auto chunks = [](int Hp, int Wp, int C) { return BATCH * (2 * Wp + 2 * (Hp - 2)) * C / 8; };
    Halo4 h0;
    h0.d[0] = {regA, 34, 34, 96};
    h0.d[1] = {regB, 34, 34, 96};
    h0.d[2] = {regC, 18, 18, 96};
    h0.d[3] = {regD, 18, 18, 192};
    h0.n = 4; h0.cum[0] = 0;
    for (int i = 0; i < 4; ++i)
        h0.cum[i + 1] = h0.cum[i] + chunks(h0.d[i].Hp, h0.d[i].Wp, h0.d[i].C);
    halo_zero_multi<<<CDIV(h0.cum[4], TPB), TPB, 0, stream>>>(h0);

    // conv1: dec -> act1 (regA)
    conv1_kernel<<<2048, 256, 0, stream>>>(dec, w1, b1, regA);
    // conv2: act1 -> act2 (regB)   BM=64 (WM2,WN2,MT2,NTW3) LA1/D3 36KB -> 4 blk/CU, grid 2048
    conv_2ph<96, 96, 32, 32, 1, 1, 2, 2, 2, 3, 1, 3, 256, 2><<<2048, 256, 0, stream>>>(regA, wt2, b2, regB);
    // re-zero act5 halo (regA reused as [18,18,192])
    Halo4 h5; h5.d[0] = {regA, 18, 18, 192}; h5.n = 1;
    h5.cum[0] = 0; h5.cum[1] = chunks(18, 18, 192);
    halo_zero_multi<<<CDIV(h5.cum[1], TPB), TPB, 0, stream>>>(h5);
    // conv3 (s2): act2 -> act3 (regC)   BM=32 (MT1,NTW3) 24KB -> grid 1024, 4 blk/CU
    conv_2ph<96, 96, 32, 32, 2, 1, 2, 2, 1, 3, 1, 3, 256, 2><<<1024, 256, 0, stream>>>(regB, wt3, b3, regC);
    // conv4: act3 -> act4 (regD)   BM=32 (MT1,NTW6) 48KB -> grid 1024, 3 blk/CU
    conv_2ph<96, 192, 16, 16, 1, 1, 2, 2, 1, 6, 1, 3, 256, 2><<<1024, 256, 0, stream>>>(regC, wt4, b4, regD);
    // re-zero act6 halo (regC reused as [10,10,192])
    Halo4 h6; h6.d[0] = {regC, 10, 10, 192}; h6.n = 1;
    h6.cum[0] = 0; h6.cum[1] = chunks(10, 10, 192);
    halo_zero_multi<<<CDIV(h6.cum[1], TPB), TPB, 0, stream>>>(h6);
    // conv5: act4 -> act5 (regA)   BM=32, grid 1024, NSTEP=54
    conv_2ph<192, 192, 16, 16, 1, 1, 2, 2, 1, 6, 1, 3, 256, 2><<<1024, 256, 0, stream>>>(regD, wt5, b5, regA);
    // conv6 (s2): act5 -> act6 (regC)   BM=16 (WM1,WN4,MT1,NTW3), grid 512
    conv_2ph<192, 192, 16, 16, 2, 1, 1, 4, 1, 3, 1, 3, 256, 2><<<512, 256, 0, stream>>>(regA, wt6, b6, regC);
    // conv7: act6 -> act7 (regD)   BM=16, grid 512
    conv_2ph<192, 192, 8, 8, 1, 1, 1, 4, 1, 3, 1, 3, 256, 2><<<512, 256, 0, stream>>>(regC, wt7, b7, regD);
    // conv8 (1x1): act7 -> act8 (regB)   BM=16, grid 512, NSTEP=6
    conv_2ph<192, 192, 8, 8, 1, 0, 1, 4, 1, 3, 1, 3, 256, 2><<<512, 256, 0, stream>>>(regD, wt8, b8, regB);
    // conv9 (1x1 192->10): act8 -> act9 fp32
    conv9_kernel<<<128, 256, 0, stream>>>(regB, wt9, b9, act9);
    // fused fc1+fc2+encode
    head_kernel<<<BATCH, 128, 0, stream>>>(act9, fw1, fb1, fw2, fb2, p11, s11, out);
}

// Round 18
// 198.229 us; speedup vs baseline: 1.1511x; 1.1511x over previous
//
#include <hip/hip_runtime.h>
#include <hip/hip_bf16.h>

#define BATCH 128
#define CDIV(a, b) (((a) + (b) - 1) / (b))

typedef __attribute__((ext_vector_type(8))) short short8;
typedef __attribute__((ext_vector_type(4))) float f32x4;

// compile-time unroll helpers
template <int V> struct ic { static constexpr int value = V; };
template <int... I> struct iseq {};
template <int N, int... I> struct mkseq : mkseq<N - 1, N - 1, I...> {};
template <int... I> struct mkseq<0, I...> { using type = iseq<I...>; };
template <class F, int... I>
__device__ __forceinline__ void unroll_all(F&& f, iseq<I...>) { (f(ic<I>{}), ...); }

// async global->LDS 16B: LDS dest = wave-uniform base + lane*16; global source per-lane
__device__ __forceinline__ void gload_lds16(const void* g, void* l) {
    __builtin_amdgcn_global_load_lds(
        (const __attribute__((address_space(1))) void*)g,
        (__attribute__((address_space(3))) void*)l, 16, 0, 0);
}

// 16B-unit swizzle sigma(u) = u ^ ((u>>2)&7) (bank spread for stride-4-unit frag reads)
__device__ __forceinline__ int sig_u(int u) { return u ^ ((u >> 2) & 7); }
__device__ __forceinline__ int inv_sig_u(int x) {
    int r0 = ((x >> 2) ^ (x >> 4)) & 1;
    int r1 = (x >> 3) & 1;
    int r2 = (x >> 4) & 1;
    return x ^ (r0 | (r1 << 1) | (r2 << 2));
}

// ---------------- zero fill (f32) ----------------
__global__ void fill0_f32(float* __restrict__ p, int n) {
    int i = blockIdx.x * blockDim.x + threadIdx.x;
    if (i < n) p[i] = 0.0f;
}

// ---------------- decode: scatter A0 -> padded NHWC f32 [B][34][34][4] ----------------
__global__ void decode_kernel(const float* __restrict__ y, const int* __restrict__ p,
                              const float* __restrict__ s, float* __restrict__ x) {
    const int n = 3073;
    int idx = blockIdx.x * blockDim.x + threadIdx.x;
    if (idx >= BATCH * n) return;
    int i = idx % n, b = idx / n;
    int pi = p[i];
    if (pi >= 3072) return;
    float v = y[(size_t)b * n + i] / s[i];
    int c = pi >> 10; int r = pi & 1023; int h = r >> 5; int w = r & 31;
    x[((size_t)(b * 34 + h + 1) * 34 + (w + 1)) * 4 + c] = v;
}

// ---------------- fused halo zero (up to 4 padded bf16 NHWC buffers) ----------------
struct HaloDesc { __hip_bfloat16* p; int Hp, Wp, C; };
struct Halo4 { HaloDesc d[4]; int cum[5]; int n; };

__global__ void halo_zero_multi(Halo4 h) {
    int idx = blockIdx.x * 256 + threadIdx.x;
    if (idx >= h.cum[h.n]) return;
    int seg = 0;
    while (idx >= h.cum[seg + 1]) ++seg;
    int local = idx - h.cum[seg];
    HaloDesc d = h.d[seg];
    int perB = (2 * d.Wp + 2 * (d.Hp - 2)) * d.C / 8;
    int b = local / perB;
    int r = (local % perB) * 8;
    int WpC = d.Wp * d.C;
    long addr;
    if (r < WpC) {
        addr = (long)(b * d.Hp) * WpC + r;
    } else if (r < 2 * WpC) {
        addr = (long)(b * d.Hp + d.Hp - 1) * WpC + (r - WpC);
    } else {
        int r3 = r - 2 * WpC;
        int sideN = (d.Hp - 2) * d.C;
        int side = r3 / sideN;
        int r4 = r3 % sideN;
        int row = 1 + r4 / d.C, c = r4 % d.C;
        addr = ((long)(b * d.Hp + row) * d.Wp + (side ? d.Wp - 1 : 0)) * d.C + c;
    }
    *(uint4*)((char*)d.p + addr * 2) = uint4{0, 0, 0, 0};
}

// ------ fused weight transform: OIHW f32 -> [pos*KS+kk][CoutPad][32] bf16 (k-chunked) ---
struct WtSeg { const float* src; __hip_bfloat16* dst; int Cout, Cin, KK, CoutPad; };
struct Wt8 { WtSeg s[8]; int cum[9]; };

__global__ void wt_transform_multi(Wt8 w) {
    int idx = blockIdx.x * 256 + threadIdx.x;
    if (idx >= w.cum[8]) return;
    int seg = 0;
    while (idx >= w.cum[seg + 1]) ++seg;
    int local = idx - w.cum[seg];
    WtSeg sg = w.s[seg];
    int c2 = local % 32; int t = local / 32;
    int co = t % sg.CoutPad; int t2 = t / sg.CoutPad;   // t2 = pos*KS + kk
    int KS = sg.Cin / 32;
    int kk = t2 % KS; int pos = t2 / KS;
    int cin = kk * 32 + c2;
    float v = (co < sg.Cout) ? sg.src[((size_t)co * sg.Cin + cin) * sg.KK + pos] : 0.0f;
    sg.dst[local] = __float2bfloat16(v);
}

// ---------------- conv1: 3->96 @32x32, fp32, 4 threads/pixel, packed stores ------------
__global__ __launch_bounds__(256) void conv1_kernel(
    const float* __restrict__ in, const float* __restrict__ w,
    const float* __restrict__ bias, __hip_bfloat16* __restrict__ out) {
    __shared__ float ws[96 * 27];
    __shared__ float bs[96];
    for (int i = threadIdx.x; i < 96 * 27; i += 256) ws[i] = w[i];
    if (threadIdx.x < 96) bs[threadIdx.x] = bias[threadIdx.x];
    __syncthreads();
    int idx = blockIdx.x * 256 + threadIdx.x;
    int q = idx & 3; int pix = idx >> 2;
    int b = pix >> 10, r = pix & 1023, oh = r >> 5, ow = r & 31;
    const float* ib = in + ((size_t)(b * 34 + oh) * 34 + ow) * 4;
    float patch[9][3];
#pragma unroll
    for (int ph = 0; ph < 3; ++ph)
#pragma unroll
        for (int pw = 0; pw < 3; ++pw) {
            float4 v = *(const float4*)(ib + ((size_t)ph * 34 + pw) * 4);
            patch[ph * 3 + pw][0] = v.x; patch[ph * 3 + pw][1] = v.y; patch[ph * 3 + pw][2] = v.z;
        }
    const int c0 = q * 24;
    float acc[24];
#pragma unroll
    for (int j = 0; j < 24; ++j) acc[j] = bs[c0 + j];
    for (int j = 0; j < 24; ++j) {
        const float* wc = &ws[(c0 + j) * 27];
#pragma unroll
        for (int ci = 0; ci < 3; ++ci)
#pragma unroll
            for (int pos = 0; pos < 9; ++pos)
                acc[j] = fmaf(patch[pos][ci], wc[ci * 9 + pos], acc[j]);
    }
    __hip_bfloat16* ob = out + ((size_t)(b * 34 + oh + 1) * 34 + ow + 1) * 96 + c0;
#pragma unroll
    for (int g = 0; g < 3; ++g) {
        union { uint4 u; unsigned short s[8]; } pk;
#pragma unroll
        for (int e = 0; e < 8; ++e) {
            __hip_bfloat16 hv = __float2bfloat16(fmaxf(acc[g * 8 + e], 0.0f));
            pk.s[e] = *(unsigned short*)&hv;
        }
        *(uint4*)(ob + g * 8) = pk.u;
    }
}

// ======== conv_2ph: shared LDS chunk ring + counted vmcnt + RAW barrier, WMxWN waves ====
// Round-15 config (LA=2, DEPTH=4, race-free) + T5 setprio around the MFMA cluster.
template <int CIN, int COUT, int HIN, int WIN, int STRIDE, int R,
          int WM, int WN, int MT, int NTW, int THREADS, int MINW>
__global__ __launch_bounds__(THREADS, MINW) void conv_2ph(
    const __hip_bfloat16* __restrict__ in,   // [B][HIN+2][WIN+2][CIN]
    const __hip_bfloat16* __restrict__ wt,   // [(2R+1)^2*KS][COUT][32]
    const float* __restrict__ bias,
    __hip_bfloat16* __restrict__ out) {      // [B][HOUT+2][WOUT+2][COUT]
    constexpr int HOUT = HIN / STRIDE, WOUT = WIN / STRIDE;
    constexpr int Hp = HIN + 2, Wp = WIN + 2;
    constexpr int Hpo = HOUT + 2, Wpo = WOUT + 2;
    constexpr int D = 2 * R + 1;
    constexpr int KS = CIN / 32;
    constexpr int NSTEP = D * D * KS;
    constexpr int WAVES = THREADS / 64;
    static_assert(WAVES == WM * WN, "wave grid");
    constexpr int BMPIX = WM * MT * 16;
    static_assert(WN * NTW * 16 == COUT, "N covers COUT");
    constexpr int AUN = BMPIX * 4;           // A 16B-units per chunk
    constexpr int BUN = COUT * 4;            // B 16B-units per chunk
    constexpr int CUN = AUN + BUN;
    constexpr int DEPTH = 4, LA = 2;         // DEPTH >= LA+2 (race-free ring)
    constexpr int LPW = CDIV(CUN, 64 * WAVES);
    constexpr int CUN_ALLOC = LPW * 64 * WAVES;   // incl. scratch tail for dummy loads

    __shared__ short8 lds[DEPTH * CUN_ALLOC];

    int wid = threadIdx.x >> 6;
    int lane = threadIdx.x & 63;
    int col = lane & 15, kgrp = lane >> 4;
    int wm = wid / WN, wn = wid % WN;
    int n0 = wn * (NTW * 16);
    int mBase = wm * (MT * 16);

    // ---- per-lane stage descriptors (source pre-inverse-swizzled) ----
    const __hip_bfloat16* aSrc[LPW];
    int bOff[LPW];
    bool isA[LPW];
#pragma unroll
    for (int i = 0; i < LPW; ++i) {
        int x = (wid * LPW + i) * 64 + lane;     // LDS unit within (padded) chunk
        if (x < AUN) {
            isA[i] = true;
            int v = inv_sig_u(x);
            int p = v >> 2, q = v & 3;
            int gp = blockIdx.x * BMPIX + p;
            int b = gp / (HOUT * WOUT);
            int r = gp % (HOUT * WOUT);
            int oh = r / WOUT, ow = r % WOUT;
            aSrc[i] = in + ((size_t)(b * Hp + oh * STRIDE + 1 - R) * Wp
                            + ow * STRIDE + 1 - R) * CIN + q * 8;
            bOff[i] = 0;
        } else {
            isA[i] = false;
            // units in [AUN, CUN): real B; units >= CUN: dummy (read chunk start)
            bOff[i] = (x < CUN) ? inv_sig_u(x - AUN) * 8 : 0;
            aSrc[i] = in;
        }
    }
    // ---- frag read offsets (swizzled, within chunk) ----
    int aRd[MT], bRd[NTW];
#pragma unroll
    for (int mt = 0; mt < MT; ++mt)
        aRd[mt] = sig_u((mBase + mt * 16 + col) * 4 + kgrp);
#pragma unroll
    for (int nt = 0; nt < NTW; ++nt)
        bRd[nt] = AUN + sig_u((n0 + nt * 16 + col) * 4 + kgrp);

    auto stepAoff = [](int s) {
        int pos = s / KS, kk = s - (s / KS) * KS;
        return ((pos / D) * Wp + (pos % D)) * CIN + kk * 32;
    };
    auto stage = [&](int s) {
        int slot = s % DEPTH;
        int aoff = stepAoff(s);
        const __hip_bfloat16* wchunk = wt + (size_t)s * (COUT * 32);
#pragma unroll
        for (int i = 0; i < LPW; ++i) {
            const __hip_bfloat16* src = isA[i] ? (aSrc[i] + aoff) : (wchunk + bOff[i]);
            gload_lds16(src, &lds[slot * CUN_ALLOC + (wid * LPW + i) * 64]);
        }
    };

    f32x4 acc[MT][NTW] = {};
    stage(0);
    if constexpr (1 < NSTEP) stage(1);

    unroll_all([&](auto sc) {
        constexpr int s = decltype(sc)::value;
        if constexpr (s + LA < NSTEP) stage(s + LA);
        constexpr int C = (s + 1 < NSTEP ? 1 : 0) + (s + 2 < NSTEP ? 1 : 0);
        asm volatile("s_waitcnt vmcnt(%0)" :: "i"(C * LPW) : "memory");
        __builtin_amdgcn_s_barrier();            // raw rendezvous, no drain
        __builtin_amdgcn_sched_barrier(0);
        constexpr int slot = s % DEPTH;
        short8 af[MT], bfr[NTW];
#pragma unroll
        for (int mt = 0; mt < MT; ++mt) af[mt] = lds[slot * CUN_ALLOC + aRd[mt]];
#pragma unroll
        for (int nt = 0; nt < NTW; ++nt) bfr[nt] = lds[slot * CUN_ALLOC + bRd[nt]];
        __builtin_amdgcn_s_setprio(1);           // T5: favor MFMA-entering wave
#pragma unroll
        for (int nt = 0; nt < NTW; ++nt)
#pragma unroll
            for (int mt = 0; mt < MT; ++mt)
                acc[mt][nt] = __builtin_amdgcn_mfma_f32_16x16x32_bf16(
                    af[mt], bfr[nt], acc[mt][nt], 0, 0, 0);
        __builtin_amdgcn_s_setprio(0);
    }, typename mkseq<NSTEP>::type{});

    // epilogue: bias + relu + bf16 store into padded NHWC
#pragma unroll
    for (int mt = 0; mt < MT; ++mt) {
#pragma unroll
        for (int nt = 0; nt < NTW; ++nt) {
            int cout = n0 + nt * 16 + col;
            float bv = bias[cout];
#pragma unroll
            for (int rg = 0; rg < 4; ++rg) {
                int p = mBase + mt * 16 + kgrp * 4 + rg;
                int gp = blockIdx.x * BMPIX + p;
                int b = gp / (HOUT * WOUT);
                int r = gp % (HOUT * WOUT);
                int oh = r / WOUT, ow = r % WOUT;
                float v = fmaxf(acc[mt][nt][rg] + bv, 0.0f);
                out[((size_t)(b * Hpo + oh + 1) * Wpo + ow + 1) * COUT + cout] =
                    __float2bfloat16(v);
            }
        }
    }
}

// ======== conv_pipe (round-10): A support tile in LDS + wave-private B DMA ring =========
template <int CIN, int COUT, int HIN, int WIN, int STRIDE, int R,
          int WN, int MT, int NTW, int LA, int DEPTH, int THREADS, int MINW>
__global__ __launch_bounds__(THREADS, MINW) void conv_pipe(
    const __hip_bfloat16* __restrict__ in,
    const __hip_bfloat16* __restrict__ wt,
    const float* __restrict__ bias,
    __hip_bfloat16* __restrict__ out) {
    constexpr int HOUT = HIN / STRIDE, WOUT = WIN / STRIDE;
    constexpr int Hp = HIN + 2, Wp = WIN + 2;
    constexpr int Hpo = HOUT + 2, Wpo = WOUT + 2;
    constexpr int D = 2 * R + 1;
    constexpr int KS = CIN / 32;
    constexpr int NSTEP = D * D * KS;
    constexpr int WAVES = THREADS / 64;
    static_assert(WAVES == WN, "one wave row");
    constexpr int BM = MT * 16;
    constexpr int BN = WN * NTW * 16;
    static_assert(BN == COUT, "block covers full N");
    static_assert(BM % WOUT == 0, "whole output rows");
    constexpr int BMR = BM / WOUT;
    constexpr int SUPR = (BMR - 1) * STRIDE + D;
    constexpr int CINU = CIN / 8;
    constexpr int UPP = CINU + 1;
    constexpr int ROWU = Wp * CINU;
    constexpr int TOTU = SUPR * ROWU;

    __shared__ short8 ldsA[SUPR * Wp * UPP];
    __shared__ short8 ldsB[WAVES * DEPTH * NTW * 64];

    int wid = threadIdx.x >> 6;
    int lane = threadIdx.x & 63;
    int col = lane & 15, kgrp = lane >> 4;
    int n0 = wid * (NTW * 16);
    int su = col * 4 + kgrp;

    auto issueChunk = [&](int c, int slot) {
        const __hip_bfloat16* src = wt + ((size_t)c * COUT + n0) * 32 + lane * 8;
#pragma unroll
        for (int nt = 0; nt < NTW; ++nt)
            gload_lds16(src + nt * (16 * 32),
                        &ldsB[((wid * DEPTH + slot) * NTW + nt) * 64]);
    };

#pragma unroll
    for (int c = 0; c < LA; ++c)
        if (c < NSTEP) issueChunk(c, c % DEPTH);

    int m0 = blockIdx.x * BM;
    int gor = m0 / WOUT;
    int b = gor / HOUT;
    int oh0 = gor % HOUT;
    int r0 = oh0 * STRIDE + (1 - R);
    const __hip_bfloat16* gsrc = in + ((size_t)(b * Hp + r0) * Wp) * CIN;
    for (int g = threadIdx.x; g < TOTU; g += THREADS) {
        int row = g / ROWU;
        int ur = g - row * ROWU;
        int pix = ur / CINU;
        int c = ur - pix * CINU;
        ldsA[(row * Wp + pix) * UPP + c] = *reinterpret_cast<const short8*>(gsrc + (size_t)g * 8);
    }
    __syncthreads();

    int abaseu[MT];
#pragma unroll
    for (int mt = 0; mt < MT; ++mt) {
        int mloc = mt * 16 + col;
        int orow = mloc / WOUT, ocol = mloc % WOUT;
        abaseu[mt] = ((orow * STRIDE) * Wp + ocol * STRIDE + (1 - R)) * UPP + kgrp;
    }

    short8 af[3][MT], bf[3][NTW];
    f32x4 acc[MT][NTW] = {};

    auto readFrags = [&](int s, auto rIC) {
        constexpr int r = decltype(rIC)::value;
        int pos = s / KS, kk = s - (s / KS) * KS;
        int poff = ((pos / D) * Wp + (pos % D)) * UPP;
#pragma unroll
        for (int mt = 0; mt < MT; ++mt)
            af[r][mt] = ldsA[abaseu[mt] + poff + kk * 4];
        int slot = s % DEPTH;
#pragma unroll
        for (int nt = 0; nt < NTW; ++nt)
            bf[r][nt] = ldsB[((wid * DEPTH + slot) * NTW + nt) * 64 + su];
    };

    readFrags(0, ic<0>{});
    if (1 < NSTEP) readFrags(1, ic<1>{});

    unroll_all([&](auto sc) {
        constexpr int s = decltype(sc)::value;
        if constexpr (s + LA < NSTEP) issueChunk(s + LA, (s + LA) % DEPTH);
        if constexpr (s + 2 < NSTEP) {
            constexpr int I = (s + LA < NSTEP - 1) ? (s + LA) : (NSTEP - 1);
            constexpr int NW0 = (I - (s + 2)) * NTW;
            constexpr int NW = NW0 < 0 ? 0 : NW0;
            asm volatile("s_waitcnt vmcnt(%0)" :: "i"(NW) : "memory");
            readFrags(s + 2, ic<(s + 2) % 3>{});
        }
        __builtin_amdgcn_s_setprio(1);
#pragma unroll
        for (int nt = 0; nt < NTW; ++nt)
#pragma unroll
            for (int mt = 0; mt < MT; ++mt)
                acc[mt][nt] = __builtin_amdgcn_mfma_f32_16x16x32_bf16(
                    af[s % 3][mt], bf[s % 3][nt], acc[mt][nt], 0, 0, 0);
        __builtin_amdgcn_s_setprio(0);
    }, typename mkseq<NSTEP>::type{});

#pragma unroll
    for (int mt = 0; mt < MT; ++mt) {
#pragma unroll
        for (int nt = 0; nt < NTW; ++nt) {
            int cout = n0 + nt * 16 + col;
            float bv = bias[cout];
#pragma unroll
            for (int rg = 0; rg < 4; ++rg) {
                int mloc = mt * 16 + kgrp * 4 + rg;
                int orow = mloc / WOUT, ocol = mloc % WOUT;
                float v = fmaxf(acc[mt][nt][rg] + bv, 0.0f);
                out[((size_t)(b * Hpo + oh0 + orow + 1) * Wpo + ocol + 1) * COUT + cout] =
                    __float2bfloat16(v);
            }
        }
    }
}

// ---------------- conv_lds (register-ring) — used for conv8 (1x1, NSTEP=6) -------------
template <int CIN, int COUT, int HIN, int WIN, int STRIDE, int R,
          int WM, int WN, int MT, int NTW, int PW, int THREADS, int MINW>
__global__ __launch_bounds__(THREADS, MINW) void conv_lds(
    const __hip_bfloat16* __restrict__ in,
    const __hip_bfloat16* __restrict__ wt,
    const float* __restrict__ bias,
    __hip_bfloat16* __restrict__ out) {
    constexpr int HOUT = HIN / STRIDE, WOUT = WIN / STRIDE;
    constexpr int Hp = HIN + 2, Wp = WIN + 2;
    constexpr int Hpo = HOUT + 2, Wpo = WOUT + 2;
    constexpr int D = 2 * R + 1;
    constexpr int KS = CIN / 32;
    constexpr int NSTEP = D * D * KS;
    constexpr int BM = WM * MT * 16;
    constexpr int BN = WN * NTW * 16;
    static_assert(BN == COUT, "block covers full N");
    static_assert(BM % WOUT == 0, "block tile = whole output rows");
    static_assert(THREADS / 64 == WM * WN, "wave count");
    constexpr int BMR = BM / WOUT;
    constexpr int SUPR = (BMR - 1) * STRIDE + D;
    constexpr int CINU = CIN / 8;
    constexpr int UPP = CINU + 1;
    constexpr int ROWU = Wp * CINU;
    constexpr int TOTU = SUPR * ROWU;

    __shared__ short8 lds[SUPR * Wp * UPP];

    int m0 = blockIdx.x * BM;
    int gor = m0 / WOUT;
    int b = gor / HOUT;
    int oh0 = gor % HOUT;
    int r0 = oh0 * STRIDE + (1 - R);

    const __hip_bfloat16* gsrc = in + ((size_t)(b * Hp + r0) * Wp) * CIN;
    for (int g = threadIdx.x; g < TOTU; g += THREADS) {
        int row = g / ROWU;
        int ur = g - row * ROWU;
        int pix = ur / CINU;
        int c = ur - pix * CINU;
        lds[(row * Wp + pix) * UPP + c] = *reinterpret_cast<const short8*>(gsrc + (size_t)g * 8);
    }
    __syncthreads();

    int wid = threadIdx.x >> 6;
    int lane = threadIdx.x & 63;
    int col = lane & 15, kgrp = lane >> 4;
    int wm = wid / WN, wn = wid % WN;
    int n0 = wn * NTW * 16;

    int apix[MT];
#pragma unroll
    for (int mt = 0; mt < MT; ++mt) {
        int mloc = (wm * MT + mt) * 16 + col;
        int orow = mloc / WOUT, ocol = mloc % WOUT;
        apix[mt] = (orow * STRIDE) * Wp + ocol * STRIDE + (1 - R);
    }
    const __hip_bfloat16* bbase[NTW];
#pragma unroll
    for (int nt = 0; nt < NTW; ++nt)
        bbase[nt] = wt + (size_t)(n0 + nt * 16 + col) * 32 + kgrp * 8;

    short8 abuf[3][MT];
    short8 bbuf[PW][NTW];
    f32x4 acc[MT][NTW] = {};

    auto ldA = [&](int s, int slot) {
        int pos = s / KS, kk = s - (s / KS) * KS;
        int dh = pos / D, dw = pos - dh * D;
        int poff = dh * Wp + dw;
#pragma unroll
        for (int mt = 0; mt < MT; ++mt)
            abuf[slot][mt] = lds[(apix[mt] + poff) * UPP + kk * 4 + kgrp];
    };
    auto ldB = [&](int s, int slot) {
        size_t off = (size_t)s * (COUT * 32);
#pragma unroll
        for (int nt = 0; nt < NTW; ++nt)
            bbuf[slot][nt] = *reinterpret_cast<const short8*>(bbase[nt] + off);
    };

#pragma unroll
    for (int s = 0; s < PW - 1; ++s)
        if (s < NSTEP) ldB(s, s);
    ldA(0, 0);
    if (1 < NSTEP) ldA(1, 1);
    __builtin_amdgcn_sched_barrier(0);

#pragma unroll
    for (int s = 0; s < NSTEP; ++s) {
        if (s + PW - 1 < NSTEP) ldB(s + PW - 1, (s + PW - 1) % PW);
        if (s + 2 < NSTEP) ldA(s + 2, (s + 2) % 3);
        __builtin_amdgcn_sched_barrier(0);
#pragma unroll
        for (int nt = 0; nt < NTW; ++nt)
#pragma unroll
            for (int mt = 0; mt < MT; ++mt)
                acc[mt][nt] = __builtin_amdgcn_mfma_f32_16x16x32_bf16(
                    abuf[s % 3][mt], bbuf[s % PW][nt], acc[mt][nt], 0, 0, 0);
    }

#pragma unroll
    for (int mt = 0; mt < MT; ++mt) {
#pragma unroll
        for (int nt = 0; nt < NTW; ++nt) {
            int cout = n0 + nt * 16 + col;
            float bv = bias[cout];
#pragma unroll
            for (int rg = 0; rg < 4; ++rg) {
                int mloc = (wm * MT + mt) * 16 + kgrp * 4 + rg;
                int orow = mloc / WOUT, ocol = mloc % WOUT;
                float v = fmaxf(acc[mt][nt][rg] + bv, 0.0f);
                out[((size_t)(b * Hpo + oh0 + orow + 1) * Wpo + ocol + 1) * COUT + cout] =
                    __float2bfloat16(v);
            }
        }
    }
}

// ---------------- conv9: 1x1 192->10 (pad16), relu, fp32 NCHW-flat out [B][640] --------
__global__ __launch_bounds__(256) void conv9_kernel(
    const __hip_bfloat16* __restrict__ in, const __hip_bfloat16* __restrict__ wt,
    const float* __restrict__ bias, float* __restrict__ out) {
    int wid = threadIdx.x >> 6;
    int lane = threadIdx.x & 63;
    int wave = blockIdx.x * 4 + wid;
    int m0 = wave * 16;
    int col = lane & 15;
    int kgrp = lane >> 4;
    int m = m0 + col;
    int b = m >> 6; int r = m & 63; int oh = r >> 3; int ow = r & 7;
    const __hip_bfloat16* abase = in + ((size_t)(b * 10 + oh + 1) * 10 + ow + 1) * 192 + kgrp * 8;
    f32x4 acc = {};
#pragma unroll
    for (int kk = 0; kk < 6; ++kk) {
        short8 bfr = *reinterpret_cast<const short8*>(wt + ((size_t)kk * 16 + col) * 32 + kgrp * 8);
        short8 a = *reinterpret_cast<const short8*>(abase + kk * 32);
        acc = __builtin_amdgcn_mfma_f32_16x16x32_bf16(a, bfr, acc, 0, 0, 0);
    }
    if (col < 10) {
        float bv = bias[col];
#pragma unroll
        for (int rg = 0; rg < 4; ++rg) {
            int m2 = m0 + kgrp * 4 + rg;
            int b2 = m2 >> 6; int r2 = m2 & 63;
            out[(size_t)b2 * 640 + col * 64 + r2] = fmaxf(acc[rg] + bv, 0.0f);
        }
    }
}

// ---------------- fused head: fc1(640->100)+relu, fc2(100->10), encode -----------------
__global__ __launch_bounds__(128) void head_kernel(
    const float* __restrict__ act9, const float* __restrict__ fw1, const float* __restrict__ fb1,
    const float* __restrict__ fw2, const float* __restrict__ fb2,
    const int* __restrict__ p11, const float* __restrict__ s11, float* __restrict__ out) {
    __shared__ float x[640];
    __shared__ float h[100];
    __shared__ float o[10];
    int b = blockIdx.x, t = threadIdx.x;
    for (int i = t; i < 160; i += 128)
        ((float4*)x)[i] = ((const float4*)(act9 + (size_t)b * 640))[i];
    __syncthreads();
    if (t < 100) {
        float acc = fb1[t];
        const float4* wr = (const float4*)(fw1 + (size_t)t * 640);
        const float4* xv = (const float4*)x;
#pragma unroll 4
        for (int i = 0; i < 160; ++i) {
            float4 wv = wr[i], qv = xv[i];
            acc = fmaf(wv.x, qv.x, acc); acc = fmaf(wv.y, qv.y, acc);
            acc = fmaf(wv.z, qv.z, acc); acc = fmaf(wv.w, qv.w, acc);
        }
        h[t] = fmaxf(acc, 0.0f);
    }
    __syncthreads();
    if (t < 10) {
        float acc = fb2[t];
        for (int i = 0; i < 100; ++i) acc = fmaf(h[i], fw2[t * 100 + i], acc);
        o[t] = acc;
    }
    __syncthreads();
    if (t < 11) {
        int pi = p11[t];
        out[(size_t)b * 11 + t] = s11[t] * (pi == 10 ? 1.0f : o[pi]);
    }
}

extern "C" void kernel_launch(void* const* d_in, const int* in_sizes, int n_in,
                              void* d_out, int out_size, void* d_ws, size_t ws_size,
                              hipStream_t stream) {
    const int*   p0  = (const int*)  d_in[0];
    const float* s0  = (const float*)d_in[1];
    const int*   p11 = (const int*)  d_in[26];
    const float* s11 = (const float*)d_in[27];
    const float* w1 = (const float*)d_in[28]; const float* b1 = (const float*)d_in[29];
    const float* w2 = (const float*)d_in[30]; const float* b2 = (const float*)d_in[31];
    const float* w3 = (const float*)d_in[32]; const float* b3 = (const float*)d_in[33];
    const float* w4 = (const float*)d_in[34]; const float* b4 = (const float*)d_in[35];
    const float* w5 = (const float*)d_in[36]; const float* b5 = (const float*)d_in[37];
    const float* w6 = (const float*)d_in[38]; const float* b6 = (const float*)d_in[39];
    const float* w7 = (const float*)d_in[40]; const float* b7 = (const float*)d_in[41];
    const float* w8 = (const float*)d_in[42]; const float* b8 = (const float*)d_in[43];
    const float* w9 = (const float*)d_in[44]; const float* b9 = (const float*)d_in[45];
    const float* fw1 = (const float*)d_in[46]; const float* fb1 = (const float*)d_in[47];
    const float* fw2 = (const float*)d_in[48]; const float* fb2 = (const float*)d_in[49];
    const float* A0 = (const float*)d_in[50];
    float* out = (float*)d_out;

    // ---- workspace carve-up (256B aligned) ----
    size_t off = 0;
    auto alloc = [&](size_t bytes) {
        void* p = (char*)d_ws + off;
        off += (bytes + 255) & ~(size_t)255;
        return p;
    };
    const size_t SZ_3434_96  = (size_t)BATCH * 34 * 34 * 96 * 2;
    const size_t SZ_1818_96  = (size_t)BATCH * 18 * 18 * 96 * 2;
    const size_t SZ_1818_192 = (size_t)BATCH * 18 * 18 * 192 * 2;

    float* dec = (float*)alloc((size_t)BATCH * 34 * 34 * 4 * 4);
    __hip_bfloat16* regA = (__hip_bfloat16*)alloc(SZ_3434_96);   // act1; act5 [18,18,192]
    __hip_bfloat16* regB = (__hip_bfloat16*)alloc(SZ_3434_96);   // act2; act8 [10,10,192]
    __hip_bfloat16* regC = (__hip_bfloat16*)alloc(SZ_1818_96);   // act3; act6 [10,10,192]
    __hip_bfloat16* regD = (__hip_bfloat16*)alloc(SZ_1818_192);  // act4; act7 [10,10,192]
    __hip_bfloat16* wt2 = (__hip_bfloat16*)alloc((size_t)9 * 96 * 96 * 2);
    __hip_bfloat16* wt3 = (__hip_bfloat16*)alloc((size_t)9 * 96 * 96 * 2);
    __hip_bfloat16* wt4 = (__hip_bfloat16*)alloc((size_t)9 * 192 * 96 * 2);
    __hip_bfloat16* wt5 = (__hip_bfloat16*)alloc((size_t)9 * 192 * 192 * 2);
    __hip_bfloat16* wt6 = (__hip_bfloat16*)alloc((size_t)9 * 192 * 192 * 2);
    __hip_bfloat16* wt7 = (__hip_bfloat16*)alloc((size_t)9 * 192 * 192 * 2);
    __hip_bfloat16* wt8 = (__hip_bfloat16*)alloc((size_t)1 * 192 * 192 * 2);
    __hip_bfloat16* wt9 = (__hip_bfloat16*)alloc((size_t)16 * 192 * 2);
    float* act9 = (float*)alloc((size_t)BATCH * 640 * 4);

    const int TPB = 256;

    // decode input
    int decN = BATCH * 34 * 34 * 4;
    fill0_f32<<<CDIV(decN, TPB), TPB, 0, stream>>>(dec, decN);
    decode_kernel<<<CDIV(BATCH * 3073, TPB), TPB, 0, stream>>>(A0, p0, s0, dec);

    // fused weight transform (k-chunk-contiguous layout)
    Wt8 wts;
    wts.s[0] = {w2, wt2, 96, 96, 9, 96};
    wts.s[1] = {w3, wt3, 96, 96, 9, 96};
    wts.s[2] = {w4, wt4, 192, 96, 9, 192};
    wts.s[3] = {w5, wt5, 192, 192, 9, 192};
    wts.s[4] = {w6, wt6, 192, 192, 9, 192};
    wts.s[5] = {w7, wt7, 192, 192, 9, 192};
    wts.s[6] = {w8, wt8, 192, 192, 1, 192};
    wts.s[7] = {w9, wt9, 10, 192, 1, 16};
    wts.cum[0] = 0;
    for (int i = 0; i < 8; ++i)
        wts.cum[i + 1] = wts.cum[i] + wts.s[i].KK * wts.s[i].CoutPad * wts.s[i].Cin;
    wt_transform_multi<<<CDIV(wts.cum[8], TPB), TPB, 0, stream>>>(wts);

    // fused halo zero: act1, act2, act3, act4
    auto chunks = [](int Hp, int Wp, int C) { return BATCH * (2 * Wp + 2 * (Hp - 2)) * C / 8; };
    Halo4 h0;
    h0.d[0] = {regA, 34, 34, 96};
    h0.d[1] = {regB, 34, 34, 96};
    h0.d[2] = {regC, 18, 18, 96};
    h0.d[3] = {regD, 18, 18, 192};
    h0.n = 4; h0.cum[0] = 0;
    for (int i = 0; i < 4; ++i)
        h0.cum[i + 1] = h0.cum[i] + chunks(h0.d[i].Hp, h0.d[i].Wp, h0.d[i].C);
    halo_zero_multi<<<CDIV(h0.cum[4], TPB), TPB, 0, stream>>>(h0);

    // conv1: dec -> act1 (regA)
    conv1_kernel<<<2048, 256, 0, stream>>>(dec, w1, b1, regA);
    // conv2: act1 -> act2 (regB)   2ph 4-wave: BM=128 (WM2,WN2,MT4,NTW3), grid 1024
    conv_2ph<96, 96, 32, 32, 1, 1, 2, 2, 4, 3, 256, 2><<<1024, 256, 0, stream>>>(regA, wt2, b2, regB);
    // re-zero act5 halo (regA reused as [18,18,192])
    Halo4 h5; h5.d[0] = {regA, 18, 18, 192}; h5.n = 1;
    h5.cum[0] = 0; h5.cum[1] = chunks(18, 18, 192);
    halo_zero_multi<<<CDIV(h5.cum[1], TPB), TPB, 0, stream>>>(h5);
    // conv3 (s2): act2 -> act3 (regC)   BM=64 (WM2,WN2,MT2,NTW3), grid 512 (2 blk/CU)
    conv_2ph<96, 96, 32, 32, 2, 1, 2, 2, 2, 3, 256, 2><<<512, 256, 0, stream>>>(regB, wt3, b3, regC);
    // conv4: act3 -> act4 (regD)   BM=64 (WM2,WN2,MT2,NTW6), grid 512
    conv_2ph<96, 192, 16, 16, 1, 1, 2, 2, 2, 6, 256, 2><<<512, 256, 0, stream>>>(regC, wt4, b4, regD);
    // re-zero act6 halo (regC reused as [10,10,192])
    Halo4 h6; h6.d[0] = {regC, 10, 10, 192}; h6.n = 1;
    h6.cum[0] = 0; h6.cum[1] = chunks(10, 10, 192);
    halo_zero_multi<<<CDIV(h6.cum[1], TPB), TPB, 0, stream>>>(h6);
    // conv5: act4 -> act5 (regA)   BM=64, grid 512, NSTEP=54
    conv_2ph<192, 192, 16, 16, 1, 1, 2, 2, 2, 6, 256, 2><<<512, 256, 0, stream>>>(regD, wt5, b5, regA);
    // conv6 (s2): act5 -> act6 (regC)   conv_pipe (small M)
    conv_pipe<192, 192, 16, 16, 2, 1, 4, 1, 3, 3, 3, 256, 2><<<512, 256, 0, stream>>>(regA, wt6, b6, regC);
    // conv7: act6 -> act7 (regD)   conv_pipe
    conv_pipe<192, 192, 8, 8, 1, 1, 4, 2, 3, 4, 4, 256, 2><<<256, 256, 0, stream>>>(regC, wt7, b7, regD);
    // conv8 (1x1): act7 -> act8 (regB)   register-ring kernel
    conv_lds<192, 192, 8, 8, 1, 0, 1, 4, 1, 3, 6, 256, 3><<<512, 256, 0, stream>>>(regD, wt8, b8, regB);
    // conv9 (1x1 192->10): act8 -> act9 fp32
    conv9_kernel<<<128, 256, 0, stream>>>(regB, wt9, b9, act9);
    // fused fc1+fc2+encode
    head_kernel<<<BATCH, 128, 0, stream>>>(act9, fw1, fb1, fw2, fb2, p11, s11, out);
}

// Round 19
// 191.363 us; speedup vs baseline: 1.1924x; 1.0359x over previous
//
#include <hip/hip_runtime.h>
#include <hip/hip_bf16.h>

#define BATCH 128
#define CDIV(a, b) (((a) + (b) - 1) / (b))

typedef __attribute__((ext_vector_type(8))) short short8;
typedef __attribute__((ext_vector_type(4))) float f32x4;

// compile-time unroll helpers
template <int V> struct ic { static constexpr int value = V; };
template <int... I> struct iseq {};
template <int N, int... I> struct mkseq : mkseq<N - 1, N - 1, I...> {};
template <int... I> struct mkseq<0, I...> { using type = iseq<I...>; };
template <class F, int... I>
__device__ __forceinline__ void unroll_all(F&& f, iseq<I...>) { (f(ic<I>{}), ...); }

// async global->LDS 16B: LDS dest = wave-uniform base + lane*16; global source per-lane
__device__ __forceinline__ void gload_lds16(const void* g, void* l) {
    __builtin_amdgcn_global_load_lds(
        (const __attribute__((address_space(1))) void*)g,
        (__attribute__((address_space(3))) void*)l, 16, 0, 0);
}

// 16B-unit swizzle sigma(u) = u ^ ((u>>2)&7) (bank spread for stride-4-unit frag reads)
__device__ __forceinline__ int sig_u(int u) { return u ^ ((u >> 2) & 7); }
__device__ __forceinline__ int inv_sig_u(int x) {
    int r0 = ((x >> 2) ^ (x >> 4)) & 1;
    int r1 = (x >> 3) & 1;
    int r2 = (x >> 4) & 1;
    return x ^ (r0 | (r1 << 1) | (r2 << 2));
}

// ---------------- zero fill (f32) ----------------
__global__ void fill0_f32(float* __restrict__ p, int n) {
    int i = blockIdx.x * blockDim.x + threadIdx.x;
    if (i < n) p[i] = 0.0f;
}

// ---------------- decode: scatter A0 -> padded NHWC f32 [B][34][34][4] ----------------
__global__ void decode_kernel(const float* __restrict__ y, const int* __restrict__ p,
                              const float* __restrict__ s, float* __restrict__ x) {
    const int n = 3073;
    int idx = blockIdx.x * blockDim.x + threadIdx.x;
    if (idx >= BATCH * n) return;
    int i = idx % n, b = idx / n;
    int pi = p[i];
    if (pi >= 3072) return;
    float v = y[(size_t)b * n + i] / s[i];
    int c = pi >> 10; int r = pi & 1023; int h = r >> 5; int w = r & 31;
    x[((size_t)(b * 34 + h + 1) * 34 + (w + 1)) * 4 + c] = v;
}

// ---------------- fused halo zero (up to 4 padded bf16 NHWC buffers) ----------------
struct HaloDesc { __hip_bfloat16* p; int Hp, Wp, C; };
struct Halo4 { HaloDesc d[4]; int cum[5]; int n; };

__global__ void halo_zero_multi(Halo4 h) {
    int idx = blockIdx.x * 256 + threadIdx.x;
    if (idx >= h.cum[h.n]) return;
    int seg = 0;
    while (idx >= h.cum[seg + 1]) ++seg;
    int local = idx - h.cum[seg];
    HaloDesc d = h.d[seg];
    int perB = (2 * d.Wp + 2 * (d.Hp - 2)) * d.C / 8;
    int b = local / perB;
    int r = (local % perB) * 8;
    int WpC = d.Wp * d.C;
    long addr;
    if (r < WpC) {
        addr = (long)(b * d.Hp) * WpC + r;
    } else if (r < 2 * WpC) {
        addr = (long)(b * d.Hp + d.Hp - 1) * WpC + (r - WpC);
    } else {
        int r3 = r - 2 * WpC;
        int sideN = (d.Hp - 2) * d.C;
        int side = r3 / sideN;
        int r4 = r3 % sideN;
        int row = 1 + r4 / d.C, c = r4 % d.C;
        addr = ((long)(b * d.Hp + row) * d.Wp + (side ? d.Wp - 1 : 0)) * d.C + c;
    }
    *(uint4*)((char*)d.p + addr * 2) = uint4{0, 0, 0, 0};
}

// ------ fused weight transform: OIHW f32 -> [pos*KS+kk][CoutPad][32] bf16 (k-chunked) ---
struct WtSeg { const float* src; __hip_bfloat16* dst; int Cout, Cin, KK, CoutPad; };
struct Wt8 { WtSeg s[8]; int cum[9]; };

__global__ void wt_transform_multi(Wt8 w) {
    int idx = blockIdx.x * 256 + threadIdx.x;
    if (idx >= w.cum[8]) return;
    int seg = 0;
    while (idx >= w.cum[seg + 1]) ++seg;
    int local = idx - w.cum[seg];
    WtSeg sg = w.s[seg];
    int c2 = local % 32; int t = local / 32;
    int co = t % sg.CoutPad; int t2 = t / sg.CoutPad;   // t2 = pos*KS + kk
    int KS = sg.Cin / 32;
    int kk = t2 % KS; int pos = t2 / KS;
    int cin = kk * 32 + c2;
    float v = (co < sg.Cout) ? sg.src[((size_t)co * sg.Cin + cin) * sg.KK + pos] : 0.0f;
    sg.dst[local] = __float2bfloat16(v);
}

// ---------------- conv1: 3->96 @32x32, fp32, 4 threads/pixel, packed stores ------------
__global__ __launch_bounds__(256) void conv1_kernel(
    const float* __restrict__ in, const float* __restrict__ w,
    const float* __restrict__ bias, __hip_bfloat16* __restrict__ out) {
    __shared__ float ws[96 * 27];
    __shared__ float bs[96];
    for (int i = threadIdx.x; i < 96 * 27; i += 256) ws[i] = w[i];
    if (threadIdx.x < 96) bs[threadIdx.x] = bias[threadIdx.x];
    __syncthreads();
    int idx = blockIdx.x * 256 + threadIdx.x;
    int q = idx & 3; int pix = idx >> 2;
    int b = pix >> 10, r = pix & 1023, oh = r >> 5, ow = r & 31;
    const float* ib = in + ((size_t)(b * 34 + oh) * 34 + ow) * 4;
    float patch[9][3];
#pragma unroll
    for (int ph = 0; ph < 3; ++ph)
#pragma unroll
        for (int pw = 0; pw < 3; ++pw) {
            float4 v = *(const float4*)(ib + ((size_t)ph * 34 + pw) * 4);
            patch[ph * 3 + pw][0] = v.x; patch[ph * 3 + pw][1] = v.y; patch[ph * 3 + pw][2] = v.z;
        }
    const int c0 = q * 24;
    float acc[24];
#pragma unroll
    for (int j = 0; j < 24; ++j) acc[j] = bs[c0 + j];
    for (int j = 0; j < 24; ++j) {
        const float* wc = &ws[(c0 + j) * 27];
#pragma unroll
        for (int ci = 0; ci < 3; ++ci)
#pragma unroll
            for (int pos = 0; pos < 9; ++pos)
                acc[j] = fmaf(patch[pos][ci], wc[ci * 9 + pos], acc[j]);
    }
    __hip_bfloat16* ob = out + ((size_t)(b * 34 + oh + 1) * 34 + ow + 1) * 96 + c0;
#pragma unroll
    for (int g = 0; g < 3; ++g) {
        union { uint4 u; unsigned short s[8]; } pk;
#pragma unroll
        for (int e = 0; e < 8; ++e) {
            __hip_bfloat16 hv = __float2bfloat16(fmaxf(acc[g * 8 + e], 0.0f));
            pk.s[e] = *(unsigned short*)&hv;
        }
        *(uint4*)(ob + g * 8) = pk.u;
    }
}

// ======== conv_2ph: shared LDS chunk ring + counted vmcnt + RAW barrier, WMxWN waves ====
// Round-15 config: LA=2, DEPTH=4 (race-free: DEPTH >= LA+2). No setprio (m190: hurts
// barrier-lockstep GEMM-style kernels).
template <int CIN, int COUT, int HIN, int WIN, int STRIDE, int R,
          int WM, int WN, int MT, int NTW, int THREADS, int MINW>
__global__ __launch_bounds__(THREADS, MINW) void conv_2ph(
    const __hip_bfloat16* __restrict__ in,   // [B][HIN+2][WIN+2][CIN]
    const __hip_bfloat16* __restrict__ wt,   // [(2R+1)^2*KS][COUT][32]
    const float* __restrict__ bias,
    __hip_bfloat16* __restrict__ out) {      // [B][HOUT+2][WOUT+2][COUT]
    constexpr int HOUT = HIN / STRIDE, WOUT = WIN / STRIDE;
    constexpr int Hp = HIN + 2, Wp = WIN + 2;
    constexpr int Hpo = HOUT + 2, Wpo = WOUT + 2;
    constexpr int D = 2 * R + 1;
    constexpr int KS = CIN / 32;
    constexpr int NSTEP = D * D * KS;
    constexpr int WAVES = THREADS / 64;
    static_assert(WAVES == WM * WN, "wave grid");
    constexpr int BMPIX = WM * MT * 16;
    static_assert(WN * NTW * 16 == COUT, "N covers COUT");
    constexpr int AUN = BMPIX * 4;           // A 16B-units per chunk
    constexpr int BUN = COUT * 4;            // B 16B-units per chunk
    constexpr int CUN = AUN + BUN;
    constexpr int DEPTH = 4, LA = 2;         // DEPTH >= LA+2 (race-free ring)
    constexpr int LPW = CDIV(CUN, 64 * WAVES);
    constexpr int CUN_ALLOC = LPW * 64 * WAVES;   // incl. scratch tail for dummy loads

    __shared__ short8 lds[DEPTH * CUN_ALLOC];

    int wid = threadIdx.x >> 6;
    int lane = threadIdx.x & 63;
    int col = lane & 15, kgrp = lane >> 4;
    int wm = wid / WN, wn = wid % WN;
    int n0 = wn * (NTW * 16);
    int mBase = wm * (MT * 16);

    // ---- per-lane stage descriptors (source pre-inverse-swizzled) ----
    const __hip_bfloat16* aSrc[LPW];
    int bOff[LPW];
    bool isA[LPW];
#pragma unroll
    for (int i = 0; i < LPW; ++i) {
        int x = (wid * LPW + i) * 64 + lane;     // LDS unit within (padded) chunk
        if (x < AUN) {
            isA[i] = true;
            int v = inv_sig_u(x);
            int p = v >> 2, q = v & 3;
            int gp = blockIdx.x * BMPIX + p;
            int b = gp / (HOUT * WOUT);
            int r = gp % (HOUT * WOUT);
            int oh = r / WOUT, ow = r % WOUT;
            aSrc[i] = in + ((size_t)(b * Hp + oh * STRIDE + 1 - R) * Wp
                            + ow * STRIDE + 1 - R) * CIN + q * 8;
            bOff[i] = 0;
        } else {
            isA[i] = false;
            // units in [AUN, CUN): real B; units >= CUN: dummy (read chunk start)
            bOff[i] = (x < CUN) ? inv_sig_u(x - AUN) * 8 : 0;
            aSrc[i] = in;
        }
    }
    // ---- frag read offsets (swizzled, within chunk) ----
    int aRd[MT], bRd[NTW];
#pragma unroll
    for (int mt = 0; mt < MT; ++mt)
        aRd[mt] = sig_u((mBase + mt * 16 + col) * 4 + kgrp);
#pragma unroll
    for (int nt = 0; nt < NTW; ++nt)
        bRd[nt] = AUN + sig_u((n0 + nt * 16 + col) * 4 + kgrp);

    auto stepAoff = [](int s) {
        int pos = s / KS, kk = s - (s / KS) * KS;
        return ((pos / D) * Wp + (pos % D)) * CIN + kk * 32;
    };
    auto stage = [&](int s) {
        int slot = s % DEPTH;
        int aoff = stepAoff(s);
        const __hip_bfloat16* wchunk = wt + (size_t)s * (COUT * 32);
#pragma unroll
        for (int i = 0; i < LPW; ++i) {
            const __hip_bfloat16* src = isA[i] ? (aSrc[i] + aoff) : (wchunk + bOff[i]);
            gload_lds16(src, &lds[slot * CUN_ALLOC + (wid * LPW + i) * 64]);
        }
    };

    f32x4 acc[MT][NTW] = {};
    stage(0);
    if constexpr (1 < NSTEP) stage(1);

    unroll_all([&](auto sc) {
        constexpr int s = decltype(sc)::value;
        if constexpr (s + LA < NSTEP) stage(s + LA);
        constexpr int C = (s + 1 < NSTEP ? 1 : 0) + (s + 2 < NSTEP ? 1 : 0);
        asm volatile("s_waitcnt vmcnt(%0)" :: "i"(C * LPW) : "memory");
        __builtin_amdgcn_s_barrier();            // raw rendezvous, no drain
        __builtin_amdgcn_sched_barrier(0);
        constexpr int slot = s % DEPTH;
        short8 af[MT], bfr[NTW];
#pragma unroll
        for (int mt = 0; mt < MT; ++mt) af[mt] = lds[slot * CUN_ALLOC + aRd[mt]];
#pragma unroll
        for (int nt = 0; nt < NTW; ++nt) bfr[nt] = lds[slot * CUN_ALLOC + bRd[nt]];
#pragma unroll
        for (int nt = 0; nt < NTW; ++nt)
#pragma unroll
            for (int mt = 0; mt < MT; ++mt)
                acc[mt][nt] = __builtin_amdgcn_mfma_f32_16x16x32_bf16(
                    af[mt], bfr[nt], acc[mt][nt], 0, 0, 0);
    }, typename mkseq<NSTEP>::type{});

    // epilogue: bias + relu + bf16 store into padded NHWC
#pragma unroll
    for (int mt = 0; mt < MT; ++mt) {
#pragma unroll
        for (int nt = 0; nt < NTW; ++nt) {
            int cout = n0 + nt * 16 + col;
            float bv = bias[cout];
#pragma unroll
            for (int rg = 0; rg < 4; ++rg) {
                int p = mBase + mt * 16 + kgrp * 4 + rg;
                int gp = blockIdx.x * BMPIX + p;
                int b = gp / (HOUT * WOUT);
                int r = gp % (HOUT * WOUT);
                int oh = r / WOUT, ow = r % WOUT;
                float v = fmaxf(acc[mt][nt][rg] + bv, 0.0f);
                out[((size_t)(b * Hpo + oh + 1) * Wpo + ow + 1) * COUT + cout] =
                    __float2bfloat16(v);
            }
        }
    }
}

// ======== conv_pipe (round-10): A support tile in LDS + wave-private B DMA ring =========
template <int CIN, int COUT, int HIN, int WIN, int STRIDE, int R,
          int WN, int MT, int NTW, int LA, int DEPTH, int THREADS, int MINW>
__global__ __launch_bounds__(THREADS, MINW) void conv_pipe(
    const __hip_bfloat16* __restrict__ in,
    const __hip_bfloat16* __restrict__ wt,
    const float* __restrict__ bias,
    __hip_bfloat16* __restrict__ out) {
    constexpr int HOUT = HIN / STRIDE, WOUT = WIN / STRIDE;
    constexpr int Hp = HIN + 2, Wp = WIN + 2;
    constexpr int Hpo = HOUT + 2, Wpo = WOUT + 2;
    constexpr int D = 2 * R + 1;
    constexpr int KS = CIN / 32;
    constexpr int NSTEP = D * D * KS;
    constexpr int WAVES = THREADS / 64;
    static_assert(WAVES == WN, "one wave row");
    constexpr int BM = MT * 16;
    constexpr int BN = WN * NTW * 16;
    static_assert(BN == COUT, "block covers full N");
    static_assert(BM % WOUT == 0, "whole output rows");
    constexpr int BMR = BM / WOUT;
    constexpr int SUPR = (BMR - 1) * STRIDE + D;
    constexpr int CINU = CIN / 8;
    constexpr int UPP = CINU + 1;
    constexpr int ROWU = Wp * CINU;
    constexpr int TOTU = SUPR * ROWU;

    __shared__ short8 ldsA[SUPR * Wp * UPP];
    __shared__ short8 ldsB[WAVES * DEPTH * NTW * 64];

    int wid = threadIdx.x >> 6;
    int lane = threadIdx.x & 63;
    int col = lane & 15, kgrp = lane >> 4;
    int n0 = wid * (NTW * 16);
    int su = col * 4 + kgrp;

    auto issueChunk = [&](int c, int slot) {
        const __hip_bfloat16* src = wt + ((size_t)c * COUT + n0) * 32 + lane * 8;
#pragma unroll
        for (int nt = 0; nt < NTW; ++nt)
            gload_lds16(src + nt * (16 * 32),
                        &ldsB[((wid * DEPTH + slot) * NTW + nt) * 64]);
    };

#pragma unroll
    for (int c = 0; c < LA; ++c)
        if (c < NSTEP) issueChunk(c, c % DEPTH);

    int m0 = blockIdx.x * BM;
    int gor = m0 / WOUT;
    int b = gor / HOUT;
    int oh0 = gor % HOUT;
    int r0 = oh0 * STRIDE + (1 - R);
    const __hip_bfloat16* gsrc = in + ((size_t)(b * Hp + r0) * Wp) * CIN;
    for (int g = threadIdx.x; g < TOTU; g += THREADS) {
        int row = g / ROWU;
        int ur = g - row * ROWU;
        int pix = ur / CINU;
        int c = ur - pix * CINU;
        ldsA[(row * Wp + pix) * UPP + c] = *reinterpret_cast<const short8*>(gsrc + (size_t)g * 8);
    }
    __syncthreads();

    int abaseu[MT];
#pragma unroll
    for (int mt = 0; mt < MT; ++mt) {
        int mloc = mt * 16 + col;
        int orow = mloc / WOUT, ocol = mloc % WOUT;
        abaseu[mt] = ((orow * STRIDE) * Wp + ocol * STRIDE + (1 - R)) * UPP + kgrp;
    }

    short8 af[3][MT], bf[3][NTW];
    f32x4 acc[MT][NTW] = {};

    auto readFrags = [&](int s, auto rIC) {
        constexpr int r = decltype(rIC)::value;
        int pos = s / KS, kk = s - (s / KS) * KS;
        int poff = ((pos / D) * Wp + (pos % D)) * UPP;
#pragma unroll
        for (int mt = 0; mt < MT; ++mt)
            af[r][mt] = ldsA[abaseu[mt] + poff + kk * 4];
        int slot = s % DEPTH;
#pragma unroll
        for (int nt = 0; nt < NTW; ++nt)
            bf[r][nt] = ldsB[((wid * DEPTH + slot) * NTW + nt) * 64 + su];
    };

    readFrags(0, ic<0>{});
    if (1 < NSTEP) readFrags(1, ic<1>{});

    unroll_all([&](auto sc) {
        constexpr int s = decltype(sc)::value;
        if constexpr (s + LA < NSTEP) issueChunk(s + LA, (s + LA) % DEPTH);
        if constexpr (s + 2 < NSTEP) {
            constexpr int I = (s + LA < NSTEP - 1) ? (s + LA) : (NSTEP - 1);
            constexpr int NW0 = (I - (s + 2)) * NTW;
            constexpr int NW = NW0 < 0 ? 0 : NW0;
            asm volatile("s_waitcnt vmcnt(%0)" :: "i"(NW) : "memory");
            readFrags(s + 2, ic<(s + 2) % 3>{});
        }
#pragma unroll
        for (int nt = 0; nt < NTW; ++nt)
#pragma unroll
            for (int mt = 0; mt < MT; ++mt)
                acc[mt][nt] = __builtin_amdgcn_mfma_f32_16x16x32_bf16(
                    af[s % 3][mt], bf[s % 3][nt], acc[mt][nt], 0, 0, 0);
    }, typename mkseq<NSTEP>::type{});

#pragma unroll
    for (int mt = 0; mt < MT; ++mt) {
#pragma unroll
        for (int nt = 0; nt < NTW; ++nt) {
            int cout = n0 + nt * 16 + col;
            float bv = bias[cout];
#pragma unroll
            for (int rg = 0; rg < 4; ++rg) {
                int mloc = mt * 16 + kgrp * 4 + rg;
                int orow = mloc / WOUT, ocol = mloc % WOUT;
                float v = fmaxf(acc[mt][nt][rg] + bv, 0.0f);
                out[((size_t)(b * Hpo + oh0 + orow + 1) * Wpo + ocol + 1) * COUT + cout] =
                    __float2bfloat16(v);
            }
        }
    }
}

// ---------------- conv_lds (register-ring) — used for conv8 (1x1, NSTEP=6) -------------
template <int CIN, int COUT, int HIN, int WIN, int STRIDE, int R,
          int WM, int WN, int MT, int NTW, int PW, int THREADS, int MINW>
__global__ __launch_bounds__(THREADS, MINW) void conv_lds(
    const __hip_bfloat16* __restrict__ in,
    const __hip_bfloat16* __restrict__ wt,
    const float* __restrict__ bias,
    __hip_bfloat16* __restrict__ out) {
    constexpr int HOUT = HIN / STRIDE, WOUT = WIN / STRIDE;
    constexpr int Hp = HIN + 2, Wp = WIN + 2;
    constexpr int Hpo = HOUT + 2, Wpo = WOUT + 2;
    constexpr int D = 2 * R + 1;
    constexpr int KS = CIN / 32;
    constexpr int NSTEP = D * D * KS;
    constexpr int BM = WM * MT * 16;
    constexpr int BN = WN * NTW * 16;
    static_assert(BN == COUT, "block covers full N");
    static_assert(BM % WOUT == 0, "block tile = whole output rows");
    static_assert(THREADS / 64 == WM * WN, "wave count");
    constexpr int BMR = BM / WOUT;
    constexpr int SUPR = (BMR - 1) * STRIDE + D;
    constexpr int CINU = CIN / 8;
    constexpr int UPP = CINU + 1;
    constexpr int ROWU = Wp * CINU;
    constexpr int TOTU = SUPR * ROWU;

    __shared__ short8 lds[SUPR * Wp * UPP];

    int m0 = blockIdx.x * BM;
    int gor = m0 / WOUT;
    int b = gor / HOUT;
    int oh0 = gor % HOUT;
    int r0 = oh0 * STRIDE + (1 - R);

    const __hip_bfloat16* gsrc = in + ((size_t)(b * Hp + r0) * Wp) * CIN;
    for (int g = threadIdx.x; g < TOTU; g += THREADS) {
        int row = g / ROWU;
        int ur = g - row * ROWU;
        int pix = ur / CINU;
        int c = ur - pix * CINU;
        lds[(row * Wp + pix) * UPP + c] = *reinterpret_cast<const short8*>(gsrc + (size_t)g * 8);
    }
    __syncthreads();

    int wid = threadIdx.x >> 6;
    int lane = threadIdx.x & 63;
    int col = lane & 15, kgrp = lane >> 4;
    int wm = wid / WN, wn = wid % WN;
    int n0 = wn * NTW * 16;

    int apix[MT];
#pragma unroll
    for (int mt = 0; mt < MT; ++mt) {
        int mloc = (wm * MT + mt) * 16 + col;
        int orow = mloc / WOUT, ocol = mloc % WOUT;
        apix[mt] = (orow * STRIDE) * Wp + ocol * STRIDE + (1 - R);
    }
    const __hip_bfloat16* bbase[NTW];
#pragma unroll
    for (int nt = 0; nt < NTW; ++nt)
        bbase[nt] = wt + (size_t)(n0 + nt * 16 + col) * 32 + kgrp * 8;

    short8 abuf[3][MT];
    short8 bbuf[PW][NTW];
    f32x4 acc[MT][NTW] = {};

    auto ldA = [&](int s, int slot) {
        int pos = s / KS, kk = s - (s / KS) * KS;
        int dh = pos / D, dw = pos - dh * D;
        int poff = dh * Wp + dw;
#pragma unroll
        for (int mt = 0; mt < MT; ++mt)
            abuf[slot][mt] = lds[(apix[mt] + poff) * UPP + kk * 4 + kgrp];
    };
    auto ldB = [&](int s, int slot) {
        size_t off = (size_t)s * (COUT * 32);
#pragma unroll
        for (int nt = 0; nt < NTW; ++nt)
            bbuf[slot][nt] = *reinterpret_cast<const short8*>(bbase[nt] + off);
    };

#pragma unroll
    for (int s = 0; s < PW - 1; ++s)
        if (s < NSTEP) ldB(s, s);
    ldA(0, 0);
    if (1 < NSTEP) ldA(1, 1);
    __builtin_amdgcn_sched_barrier(0);

#pragma unroll
    for (int s = 0; s < NSTEP; ++s) {
        if (s + PW - 1 < NSTEP) ldB(s + PW - 1, (s + PW - 1) % PW);
        if (s + 2 < NSTEP) ldA(s + 2, (s + 2) % 3);
        __builtin_amdgcn_sched_barrier(0);
#pragma unroll
        for (int nt = 0; nt < NTW; ++nt)
#pragma unroll
            for (int mt = 0; mt < MT; ++mt)
                acc[mt][nt] = __builtin_amdgcn_mfma_f32_16x16x32_bf16(
                    abuf[s % 3][mt], bbuf[s % PW][nt], acc[mt][nt], 0, 0, 0);
    }

#pragma unroll
    for (int mt = 0; mt < MT; ++mt) {
#pragma unroll
        for (int nt = 0; nt < NTW; ++nt) {
            int cout = n0 + nt * 16 + col;
            float bv = bias[cout];
#pragma unroll
            for (int rg = 0; rg < 4; ++rg) {
                int mloc = (wm * MT + mt) * 16 + kgrp * 4 + rg;
                int orow = mloc / WOUT, ocol = mloc % WOUT;
                float v = fmaxf(acc[mt][nt][rg] + bv, 0.0f);
                out[((size_t)(b * Hpo + oh0 + orow + 1) * Wpo + ocol + 1) * COUT + cout] =
                    __float2bfloat16(v);
            }
        }
    }
}

// ---------------- conv9: 1x1 192->10 (pad16), relu, fp32 NCHW-flat out [B][640] --------
__global__ __launch_bounds__(256) void conv9_kernel(
    const __hip_bfloat16* __restrict__ in, const __hip_bfloat16* __restrict__ wt,
    const float* __restrict__ bias, float* __restrict__ out) {
    int wid = threadIdx.x >> 6;
    int lane = threadIdx.x & 63;
    int wave = blockIdx.x * 4 + wid;
    int m0 = wave * 16;
    int col = lane & 15;
    int kgrp = lane >> 4;
    int m = m0 + col;
    int b = m >> 6; int r = m & 63; int oh = r >> 3; int ow = r & 7;
    const __hip_bfloat16* abase = in + ((size_t)(b * 10 + oh + 1) * 10 + ow + 1) * 192 + kgrp * 8;
    f32x4 acc = {};
#pragma unroll
    for (int kk = 0; kk < 6; ++kk) {
        short8 bfr = *reinterpret_cast<const short8*>(wt + ((size_t)kk * 16 + col) * 32 + kgrp * 8);
        short8 a = *reinterpret_cast<const short8*>(abase + kk * 32);
        acc = __builtin_amdgcn_mfma_f32_16x16x32_bf16(a, bfr, acc, 0, 0, 0);
    }
    if (col < 10) {
        float bv = bias[col];
#pragma unroll
        for (int rg = 0; rg < 4; ++rg) {
            int m2 = m0 + kgrp * 4 + rg;
            int b2 = m2 >> 6; int r2 = m2 & 63;
            out[(size_t)b2 * 640 + col * 64 + r2] = fmaxf(acc[rg] + bv, 0.0f);
        }
    }
}

// ---------------- fused head: fc1(640->100)+relu, fc2(100->10), encode -----------------
__global__ __launch_bounds__(128) void head_kernel(
    const float* __restrict__ act9, const float* __restrict__ fw1, const float* __restrict__ fb1,
    const float* __restrict__ fw2, const float* __restrict__ fb2,
    const int* __restrict__ p11, const float* __restrict__ s11, float* __restrict__ out) {
    __shared__ float x[640];
    __shared__ float h[100];
    __shared__ float o[10];
    int b = blockIdx.x, t = threadIdx.x;
    for (int i = t; i < 160; i += 128)
        ((float4*)x)[i] = ((const float4*)(act9 + (size_t)b * 640))[i];
    __syncthreads();
    if (t < 100) {
        float acc = fb1[t];
        const float4* wr = (const float4*)(fw1 + (size_t)t * 640);
        const float4* xv = (const float4*)x;
#pragma unroll 4
        for (int i = 0; i < 160; ++i) {
            float4 wv = wr[i], qv = xv[i];
            acc = fmaf(wv.x, qv.x, acc); acc = fmaf(wv.y, qv.y, acc);
            acc = fmaf(wv.z, qv.z, acc); acc = fmaf(wv.w, qv.w, acc);
        }
        h[t] = fmaxf(acc, 0.0f);
    }
    __syncthreads();
    if (t < 10) {
        float acc = fb2[t];
        for (int i = 0; i < 100; ++i) acc = fmaf(h[i], fw2[t * 100 + i], acc);
        o[t] = acc;
    }
    __syncthreads();
    if (t < 11) {
        int pi = p11[t];
        out[(size_t)b * 11 + t] = s11[t] * (pi == 10 ? 1.0f : o[pi]);
    }
}

extern "C" void kernel_launch(void* const* d_in, const int* in_sizes, int n_in,
                              void* d_out, int out_size, void* d_ws, size_t ws_size,
                              hipStream_t stream) {
    const int*   p0  = (const int*)  d_in[0];
    const float* s0  = (const float*)d_in[1];
    const int*   p11 = (const int*)  d_in[26];
    const float* s11 = (const float*)d_in[27];
    const float* w1 = (const float*)d_in[28]; const float* b1 = (const float*)d_in[29];
    const float* w2 = (const float*)d_in[30]; const float* b2 = (const float*)d_in[31];
    const float* w3 = (const float*)d_in[32]; const float* b3 = (const float*)d_in[33];
    const float* w4 = (const float*)d_in[34]; const float* b4 = (const float*)d_in[35];
    const float* w5 = (const float*)d_in[36]; const float* b5 = (const float*)d_in[37];
    const float* w6 = (const float*)d_in[38]; const float* b6 = (const float*)d_in[39];
    const float* w7 = (const float*)d_in[40]; const float* b7 = (const float*)d_in[41];
    const float* w8 = (const float*)d_in[42]; const float* b8 = (const float*)d_in[43];
    const float* w9 = (const float*)d_in[44]; const float* b9 = (const float*)d_in[45];
    const float* fw1 = (const float*)d_in[46]; const float* fb1 = (const float*)d_in[47];
    const float* fw2 = (const float*)d_in[48]; const float* fb2 = (const float*)d_in[49];
    const float* A0 = (const float*)d_in[50];
    float* out = (float*)d_out;

    // ---- workspace carve-up (256B aligned) ----
    size_t off = 0;
    auto alloc = [&](size_t bytes) {
        void* p = (char*)d_ws + off;
        off += (bytes + 255) & ~(size_t)255;
        return p;
    };
    const size_t SZ_3434_96  = (size_t)BATCH * 34 * 34 * 96 * 2;
    const size_t SZ_1818_96  = (size_t)BATCH * 18 * 18 * 96 * 2;
    const size_t SZ_1818_192 = (size_t)BATCH * 18 * 18 * 192 * 2;

    float* dec = (float*)alloc((size_t)BATCH * 34 * 34 * 4 * 4);
    __hip_bfloat16* regA = (__hip_bfloat16*)alloc(SZ_3434_96);   // act1; act5 [18,18,192]
    __hip_bfloat16* regB = (__hip_bfloat16*)alloc(SZ_3434_96);   // act2; act8 [10,10,192]
    __hip_bfloat16* regC = (__hip_bfloat16*)alloc(SZ_1818_96);   // act3; act6 [10,10,192]
    __hip_bfloat16* regD = (__hip_bfloat16*)alloc(SZ_1818_192);  // act4; act7 [10,10,192]
    __hip_bfloat16* wt2 = (__hip_bfloat16*)alloc((size_t)9 * 96 * 96 * 2);
    __hip_bfloat16* wt3 = (__hip_bfloat16*)alloc((size_t)9 * 96 * 96 * 2);
    __hip_bfloat16* wt4 = (__hip_bfloat16*)alloc((size_t)9 * 192 * 96 * 2);
    __hip_bfloat16* wt5 = (__hip_bfloat16*)alloc((size_t)9 * 192 * 192 * 2);
    __hip_bfloat16* wt6 = (__hip_bfloat16*)alloc((size_t)9 * 192 * 192 * 2);
    __hip_bfloat16* wt7 = (__hip_bfloat16*)alloc((size_t)9 * 192 * 192 * 2);
    __hip_bfloat16* wt8 = (__hip_bfloat16*)alloc((size_t)1 * 192 * 192 * 2);
    __hip_bfloat16* wt9 = (__hip_bfloat16*)alloc((size_t)16 * 192 * 2);
    float* act9 = (float*)alloc((size_t)BATCH * 640 * 4);

    const int TPB = 256;

    // decode input
    int decN = BATCH * 34 * 34 * 4;
    fill0_f32<<<CDIV(decN, TPB), TPB, 0, stream>>>(dec, decN);
    decode_kernel<<<CDIV(BATCH * 3073, TPB), TPB, 0, stream>>>(A0, p0, s0, dec);

    // fused weight transform (k-chunk-contiguous layout)
    Wt8 wts;
    wts.s[0] = {w2, wt2, 96, 96, 9, 96};
    wts.s[1] = {w3, wt3, 96, 96, 9, 96};
    wts.s[2] = {w4, wt4, 192, 96, 9, 192};
    wts.s[3] = {w5, wt5, 192, 192, 9, 192};
    wts.s[4] = {w6, wt6, 192, 192, 9, 192};
    wts.s[5] = {w7, wt7, 192, 192, 9, 192};
    wts.s[6] = {w8, wt8, 192, 192, 1, 192};
    wts.s[7] = {w9, wt9, 10, 192, 1, 16};
    wts.cum[0] = 0;
    for (int i = 0; i < 8; ++i)
        wts.cum[i + 1] = wts.cum[i] + wts.s[i].KK * wts.s[i].CoutPad * wts.s[i].Cin;
    wt_transform_multi<<<CDIV(wts.cum[8], TPB), TPB, 0, stream>>>(wts);

    // fused halo zero: act1, act2, act3, act4
    auto chunks = [](int Hp, int Wp, int C) { return BATCH * (2 * Wp + 2 * (Hp - 2)) * C / 8; };
    Halo4 h0;
    h0.d[0] = {regA, 34, 34, 96};
    h0.d[1] = {regB, 34, 34, 96};
    h0.d[2] = {regC, 18, 18, 96};
    h0.d[3] = {regD, 18, 18, 192};
    h0.n = 4; h0.cum[0] = 0;
    for (int i = 0; i < 4; ++i)
        h0.cum[i + 1] = h0.cum[i] + chunks(h0.d[i].Hp, h0.d[i].Wp, h0.d[i].C);
    halo_zero_multi<<<CDIV(h0.cum[4], TPB), TPB, 0, stream>>>(h0);

    // conv1: dec -> act1 (regA)
    conv1_kernel<<<2048, 256, 0, stream>>>(dec, w1, b1, regA);
    // conv2: act1 -> act2 (regB)   2ph 4-wave: BM=128 (WM2,WN2,MT4,NTW3), grid 1024
    conv_2ph<96, 96, 32, 32, 1, 1, 2, 2, 4, 3, 256, 2><<<1024, 256, 0, stream>>>(regA, wt2, b2, regB);
    // conv3 (s2): act2 -> act3 (regC)   BM=64 (WM2,WN2,MT2,NTW3), grid 512 (2 blk/CU)
    conv_2ph<96, 96, 32, 32, 2, 1, 2, 2, 2, 3, 256, 2><<<512, 256, 0, stream>>>(regB, wt3, b3, regC);
    // conv4: act3 -> act4 (regD)   BM=64 (WM2,WN2,MT2,NTW6), grid 512
    conv_2ph<96, 192, 16, 16, 1, 1, 2, 2, 2, 6, 256, 2><<<512, 256, 0, stream>>>(regC, wt4, b4, regD);
    // merged halo re-zero: act5 (regA, free after conv2) + act6 (regC, free after conv4)
    Halo4 h56;
    h56.d[0] = {regA, 18, 18, 192};
    h56.d[1] = {regC, 10, 10, 192};
    h56.n = 2; h56.cum[0] = 0;
    h56.cum[1] = chunks(18, 18, 192);
    h56.cum[2] = h56.cum[1] + chunks(10, 10, 192);
    halo_zero_multi<<<CDIV(h56.cum[2], TPB), TPB, 0, stream>>>(h56);
    // conv5: act4 -> act5 (regA)   BM=64, grid 512, NSTEP=54
    conv_2ph<192, 192, 16, 16, 1, 1, 2, 2, 2, 6, 256, 2><<<512, 256, 0, stream>>>(regD, wt5, b5, regA);
    // conv6 (s2): act5 -> act6 (regC)   conv_pipe (small M)
    conv_pipe<192, 192, 16, 16, 2, 1, 4, 1, 3, 3, 3, 256, 2><<<512, 256, 0, stream>>>(regA, wt6, b6, regC);
    // conv7: act6 -> act7 (regD)   conv_pipe
    conv_pipe<192, 192, 8, 8, 1, 1, 4, 2, 3, 4, 4, 256, 2><<<256, 256, 0, stream>>>(regC, wt7, b7, regD);
    // conv8 (1x1): act7 -> act8 (regB)   register-ring kernel
    conv_lds<192, 192, 8, 8, 1, 0, 1, 4, 1, 3, 6, 256, 3><<<512, 256, 0, stream>>>(regD, wt8, b8, regB);
    // conv9 (1x1 192->10): act8 -> act9 fp32
    conv9_kernel<<<128, 256, 0, stream>>>(regB, wt9, b9, act9);
    // fused fc1+fc2+encode
    head_kernel<<<BATCH, 128, 0, stream>>>(act9, fw1, fb1, fw2, fb2, p11, s11, out);
}

// Round 20
// 189.374 us; speedup vs baseline: 1.2049x; 1.0105x over previous
//
#include <hip/hip_runtime.h>
#include <hip/hip_bf16.h>

#define BATCH 128
#define CDIV(a, b) (((a) + (b) - 1) / (b))

typedef __attribute__((ext_vector_type(8))) short short8;
typedef __attribute__((ext_vector_type(4))) float f32x4;

// compile-time unroll helpers
template <int V> struct ic { static constexpr int value = V; };
template <int... I> struct iseq {};
template <int N, int... I> struct mkseq : mkseq<N - 1, N - 1, I...> {};
template <int... I> struct mkseq<0, I...> { using type = iseq<I...>; };
template <class F, int... I>
__device__ __forceinline__ void unroll_all(F&& f, iseq<I...>) { (f(ic<I>{}), ...); }

// async global->LDS 16B: LDS dest = wave-uniform base + lane*16; global source per-lane
__device__ __forceinline__ void gload_lds16(const void* g, void* l) {
    __builtin_amdgcn_global_load_lds(
        (const __attribute__((address_space(1))) void*)g,
        (__attribute__((address_space(3))) void*)l, 16, 0, 0);
}

// 16B-unit swizzle sigma(u) = u ^ ((u>>2)&7) (bank spread for stride-4-unit frag reads)
__device__ __forceinline__ int sig_u(int u) { return u ^ ((u >> 2) & 7); }
__device__ __forceinline__ int inv_sig_u(int x) {
    int r0 = ((x >> 2) ^ (x >> 4)) & 1;
    int r1 = (x >> 3) & 1;
    int r2 = (x >> 4) & 1;
    return x ^ (r0 | (r1 << 1) | (r2 << 2));
}

// ---------------- zero fill (f32) ----------------
__global__ void fill0_f32(float* __restrict__ p, int n) {
    int i = blockIdx.x * blockDim.x + threadIdx.x;
    if (i < n) p[i] = 0.0f;
}

// ---------------- decode: scatter A0 -> padded NHWC f32 [B][34][34][4] ----------------
__global__ void decode_kernel(const float* __restrict__ y, const int* __restrict__ p,
                              const float* __restrict__ s, float* __restrict__ x) {
    const int n = 3073;
    int idx = blockIdx.x * blockDim.x + threadIdx.x;
    if (idx >= BATCH * n) return;
    int i = idx % n, b = idx / n;
    int pi = p[i];
    if (pi >= 3072) return;
    float v = y[(size_t)b * n + i] / s[i];
    int c = pi >> 10; int r = pi & 1023; int h = r >> 5; int w = r & 31;
    x[((size_t)(b * 34 + h + 1) * 34 + (w + 1)) * 4 + c] = v;
}

// ---------------- fused halo zero (up to 4 padded bf16 NHWC buffers) ----------------
struct HaloDesc { __hip_bfloat16* p; int Hp, Wp, C; };
struct Halo4 { HaloDesc d[4]; int cum[5]; int n; };

__global__ void halo_zero_multi(Halo4 h) {
    int idx = blockIdx.x * 256 + threadIdx.x;
    if (idx >= h.cum[h.n]) return;
    int seg = 0;
    while (idx >= h.cum[seg + 1]) ++seg;
    int local = idx - h.cum[seg];
    HaloDesc d = h.d[seg];
    int perB = (2 * d.Wp + 2 * (d.Hp - 2)) * d.C / 8;
    int b = local / perB;
    int r = (local % perB) * 8;
    int WpC = d.Wp * d.C;
    long addr;
    if (r < WpC) {
        addr = (long)(b * d.Hp) * WpC + r;
    } else if (r < 2 * WpC) {
        addr = (long)(b * d.Hp + d.Hp - 1) * WpC + (r - WpC);
    } else {
        int r3 = r - 2 * WpC;
        int sideN = (d.Hp - 2) * d.C;
        int side = r3 / sideN;
        int r4 = r3 % sideN;
        int row = 1 + r4 / d.C, c = r4 % d.C;
        addr = ((long)(b * d.Hp + row) * d.Wp + (side ? d.Wp - 1 : 0)) * d.C + c;
    }
    *(uint4*)((char*)d.p + addr * 2) = uint4{0, 0, 0, 0};
}

// ------ fused weight transform: OIHW f32 -> [pos*KS+kk][CoutPad][32] bf16 (k-chunked) ---
struct WtSeg { const float* src; __hip_bfloat16* dst; int Cout, Cin, KK, CoutPad; };
struct Wt8 { WtSeg s[8]; int cum[9]; };

__global__ void wt_transform_multi(Wt8 w) {
    int idx = blockIdx.x * 256 + threadIdx.x;
    if (idx >= w.cum[8]) return;
    int seg = 0;
    while (idx >= w.cum[seg + 1]) ++seg;
    int local = idx - w.cum[seg];
    WtSeg sg = w.s[seg];
    int c2 = local % 32; int t = local / 32;
    int co = t % sg.CoutPad; int t2 = t / sg.CoutPad;   // t2 = pos*KS + kk
    int KS = sg.Cin / 32;
    int kk = t2 % KS; int pos = t2 / KS;
    int cin = kk * 32 + c2;
    float v = (co < sg.Cout) ? sg.src[((size_t)co * sg.Cin + cin) * sg.KK + pos] : 0.0f;
    sg.dst[local] = __float2bfloat16(v);
}

// ---------------- conv1: 3->96 @32x32, fp32, 4 threads/pixel, packed stores ------------
__global__ __launch_bounds__(256) void conv1_kernel(
    const float* __restrict__ in, const float* __restrict__ w,
    const float* __restrict__ bias, __hip_bfloat16* __restrict__ out) {
    __shared__ float ws[96 * 27];
    __shared__ float bs[96];
    for (int i = threadIdx.x; i < 96 * 27; i += 256) ws[i] = w[i];
    if (threadIdx.x < 96) bs[threadIdx.x] = bias[threadIdx.x];
    __syncthreads();
    int idx = blockIdx.x * 256 + threadIdx.x;
    int q = idx & 3; int pix = idx >> 2;
    int b = pix >> 10, r = pix & 1023, oh = r >> 5, ow = r & 31;
    const float* ib = in + ((size_t)(b * 34 + oh) * 34 + ow) * 4;
    float patch[9][3];
#pragma unroll
    for (int ph = 0; ph < 3; ++ph)
#pragma unroll
        for (int pw = 0; pw < 3; ++pw) {
            float4 v = *(const float4*)(ib + ((size_t)ph * 34 + pw) * 4);
            patch[ph * 3 + pw][0] = v.x; patch[ph * 3 + pw][1] = v.y; patch[ph * 3 + pw][2] = v.z;
        }
    const int c0 = q * 24;
    float acc[24];
#pragma unroll
    for (int j = 0; j < 24; ++j) acc[j] = bs[c0 + j];
    for (int j = 0; j < 24; ++j) {
        const float* wc = &ws[(c0 + j) * 27];
#pragma unroll
        for (int ci = 0; ci < 3; ++ci)
#pragma unroll
            for (int pos = 0; pos < 9; ++pos)
                acc[j] = fmaf(patch[pos][ci], wc[ci * 9 + pos], acc[j]);
    }
    __hip_bfloat16* ob = out + ((size_t)(b * 34 + oh + 1) * 34 + ow + 1) * 96 + c0;
#pragma unroll
    for (int g = 0; g < 3; ++g) {
        union { uint4 u; unsigned short s[8]; } pk;
#pragma unroll
        for (int e = 0; e < 8; ++e) {
            __hip_bfloat16 hv = __float2bfloat16(fmaxf(acc[g * 8 + e], 0.0f));
            pk.s[e] = *(unsigned short*)&hv;
        }
        *(uint4*)(ob + g * 8) = pk.u;
    }
}

// ======== conv_2ph: shared LDS chunk ring + counted vmcnt + RAW barrier, WMxWN waves ====
// LA=2, DEPTH=4 (race-free: DEPTH >= LA+2). 512-thread variants (8 waves) double
// waves/CU at identical LDS footprint (LDS is the binding resource, not threads).
template <int CIN, int COUT, int HIN, int WIN, int STRIDE, int R,
          int WM, int WN, int MT, int NTW, int THREADS, int MINW>
__global__ __launch_bounds__(THREADS, MINW) void conv_2ph(
    const __hip_bfloat16* __restrict__ in,   // [B][HIN+2][WIN+2][CIN]
    const __hip_bfloat16* __restrict__ wt,   // [(2R+1)^2*KS][COUT][32]
    const float* __restrict__ bias,
    __hip_bfloat16* __restrict__ out) {      // [B][HOUT+2][WOUT+2][COUT]
    constexpr int HOUT = HIN / STRIDE, WOUT = WIN / STRIDE;
    constexpr int Hp = HIN + 2, Wp = WIN + 2;
    constexpr int Hpo = HOUT + 2, Wpo = WOUT + 2;
    constexpr int D = 2 * R + 1;
    constexpr int KS = CIN / 32;
    constexpr int NSTEP = D * D * KS;
    constexpr int WAVES = THREADS / 64;
    static_assert(WAVES == WM * WN, "wave grid");
    constexpr int BMPIX = WM * MT * 16;
    static_assert(WN * NTW * 16 == COUT, "N covers COUT");
    constexpr int AUN = BMPIX * 4;           // A 16B-units per chunk
    constexpr int BUN = COUT * 4;            // B 16B-units per chunk
    constexpr int CUN = AUN + BUN;
    constexpr int DEPTH = 4, LA = 2;         // DEPTH >= LA+2 (race-free ring)
    constexpr int LPW = CDIV(CUN, 64 * WAVES);
    constexpr int CUN_ALLOC = LPW * 64 * WAVES;   // incl. scratch tail for dummy loads

    __shared__ short8 lds[DEPTH * CUN_ALLOC];

    int wid = threadIdx.x >> 6;
    int lane = threadIdx.x & 63;
    int col = lane & 15, kgrp = lane >> 4;
    int wm = wid / WN, wn = wid % WN;
    int n0 = wn * (NTW * 16);
    int mBase = wm * (MT * 16);

    // ---- per-lane stage descriptors (source pre-inverse-swizzled) ----
    const __hip_bfloat16* aSrc[LPW];
    int bOff[LPW];
    bool isA[LPW];
#pragma unroll
    for (int i = 0; i < LPW; ++i) {
        int x = (wid * LPW + i) * 64 + lane;     // LDS unit within (padded) chunk
        if (x < AUN) {
            isA[i] = true;
            int v = inv_sig_u(x);
            int p = v >> 2, q = v & 3;
            int gp = blockIdx.x * BMPIX + p;
            int b = gp / (HOUT * WOUT);
            int r = gp % (HOUT * WOUT);
            int oh = r / WOUT, ow = r % WOUT;
            aSrc[i] = in + ((size_t)(b * Hp + oh * STRIDE + 1 - R) * Wp
                            + ow * STRIDE + 1 - R) * CIN + q * 8;
            bOff[i] = 0;
        } else {
            isA[i] = false;
            // units in [AUN, CUN): real B; units >= CUN: dummy (read chunk start)
            bOff[i] = (x < CUN) ? inv_sig_u(x - AUN) * 8 : 0;
            aSrc[i] = in;
        }
    }
    // ---- frag read offsets (swizzled, within chunk) ----
    int aRd[MT], bRd[NTW];
#pragma unroll
    for (int mt = 0; mt < MT; ++mt)
        aRd[mt] = sig_u((mBase + mt * 16 + col) * 4 + kgrp);
#pragma unroll
    for (int nt = 0; nt < NTW; ++nt)
        bRd[nt] = AUN + sig_u((n0 + nt * 16 + col) * 4 + kgrp);

    auto stepAoff = [](int s) {
        int pos = s / KS, kk = s - (s / KS) * KS;
        return ((pos / D) * Wp + (pos % D)) * CIN + kk * 32;
    };
    auto stage = [&](int s) {
        int slot = s % DEPTH;
        int aoff = stepAoff(s);
        const __hip_bfloat16* wchunk = wt + (size_t)s * (COUT * 32);
#pragma unroll
        for (int i = 0; i < LPW; ++i) {
            const __hip_bfloat16* src = isA[i] ? (aSrc[i] + aoff) : (wchunk + bOff[i]);
            gload_lds16(src, &lds[slot * CUN_ALLOC + (wid * LPW + i) * 64]);
        }
    };

    f32x4 acc[MT][NTW] = {};
    stage(0);
    if constexpr (1 < NSTEP) stage(1);

    unroll_all([&](auto sc) {
        constexpr int s = decltype(sc)::value;
        if constexpr (s + LA < NSTEP) stage(s + LA);
        constexpr int C = (s + 1 < NSTEP ? 1 : 0) + (s + 2 < NSTEP ? 1 : 0);
        asm volatile("s_waitcnt vmcnt(%0)" :: "i"(C * LPW) : "memory");
        __builtin_amdgcn_s_barrier();            // raw rendezvous, no drain
        __builtin_amdgcn_sched_barrier(0);
        constexpr int slot = s % DEPTH;
        short8 af[MT], bfr[NTW];
#pragma unroll
        for (int mt = 0; mt < MT; ++mt) af[mt] = lds[slot * CUN_ALLOC + aRd[mt]];
#pragma unroll
        for (int nt = 0; nt < NTW; ++nt) bfr[nt] = lds[slot * CUN_ALLOC + bRd[nt]];
#pragma unroll
        for (int nt = 0; nt < NTW; ++nt)
#pragma unroll
            for (int mt = 0; mt < MT; ++mt)
                acc[mt][nt] = __builtin_amdgcn_mfma_f32_16x16x32_bf16(
                    af[mt], bfr[nt], acc[mt][nt], 0, 0, 0);
    }, typename mkseq<NSTEP>::type{});

    // epilogue: bias + relu + bf16 store into padded NHWC
#pragma unroll
    for (int mt = 0; mt < MT; ++mt) {
#pragma unroll
        for (int nt = 0; nt < NTW; ++nt) {
            int cout = n0 + nt * 16 + col;
            float bv = bias[cout];
#pragma unroll
            for (int rg = 0; rg < 4; ++rg) {
                int p = mBase + mt * 16 + kgrp * 4 + rg;
                int gp = blockIdx.x * BMPIX + p;
                int b = gp / (HOUT * WOUT);
                int r = gp % (HOUT * WOUT);
                int oh = r / WOUT, ow = r % WOUT;
                float v = fmaxf(acc[mt][nt][rg] + bv, 0.0f);
                out[((size_t)(b * Hpo + oh + 1) * Wpo + ow + 1) * COUT + cout] =
                    __float2bfloat16(v);
            }
        }
    }
}

// ======== conv_pipe (round-10): A support tile in LDS + wave-private B DMA ring =========
template <int CIN, int COUT, int HIN, int WIN, int STRIDE, int R,
          int WN, int MT, int NTW, int LA, int DEPTH, int THREADS, int MINW>
__global__ __launch_bounds__(THREADS, MINW) void conv_pipe(
    const __hip_bfloat16* __restrict__ in,
    const __hip_bfloat16* __restrict__ wt,
    const float* __restrict__ bias,
    __hip_bfloat16* __restrict__ out) {
    constexpr int HOUT = HIN / STRIDE, WOUT = WIN / STRIDE;
    constexpr int Hp = HIN + 2, Wp = WIN + 2;
    constexpr int Hpo = HOUT + 2, Wpo = WOUT + 2;
    constexpr int D = 2 * R + 1;
    constexpr int KS = CIN / 32;
    constexpr int NSTEP = D * D * KS;
    constexpr int WAVES = THREADS / 64;
    static_assert(WAVES == WN, "one wave row");
    constexpr int BM = MT * 16;
    constexpr int BN = WN * NTW * 16;
    static_assert(BN == COUT, "block covers full N");
    static_assert(BM % WOUT == 0, "whole output rows");
    constexpr int BMR = BM / WOUT;
    constexpr int SUPR = (BMR - 1) * STRIDE + D;
    constexpr int CINU = CIN / 8;
    constexpr int UPP = CINU + 1;
    constexpr int ROWU = Wp * CINU;
    constexpr int TOTU = SUPR * ROWU;

    __shared__ short8 ldsA[SUPR * Wp * UPP];
    __shared__ short8 ldsB[WAVES * DEPTH * NTW * 64];

    int wid = threadIdx.x >> 6;
    int lane = threadIdx.x & 63;
    int col = lane & 15, kgrp = lane >> 4;
    int n0 = wid * (NTW * 16);
    int su = col * 4 + kgrp;

    auto issueChunk = [&](int c, int slot) {
        const __hip_bfloat16* src = wt + ((size_t)c * COUT + n0) * 32 + lane * 8;
#pragma unroll
        for (int nt = 0; nt < NTW; ++nt)
            gload_lds16(src + nt * (16 * 32),
                        &ldsB[((wid * DEPTH + slot) * NTW + nt) * 64]);
    };

#pragma unroll
    for (int c = 0; c < LA; ++c)
        if (c < NSTEP) issueChunk(c, c % DEPTH);

    int m0 = blockIdx.x * BM;
    int gor = m0 / WOUT;
    int b = gor / HOUT;
    int oh0 = gor % HOUT;
    int r0 = oh0 * STRIDE + (1 - R);
    const __hip_bfloat16* gsrc = in + ((size_t)(b * Hp + r0) * Wp) * CIN;
    for (int g = threadIdx.x; g < TOTU; g += THREADS) {
        int row = g / ROWU;
        int ur = g - row * ROWU;
        int pix = ur / CINU;
        int c = ur - pix * CINU;
        ldsA[(row * Wp + pix) * UPP + c] = *reinterpret_cast<const short8*>(gsrc + (size_t)g * 8);
    }
    __syncthreads();

    int abaseu[MT];
#pragma unroll
    for (int mt = 0; mt < MT; ++mt) {
        int mloc = mt * 16 + col;
        int orow = mloc / WOUT, ocol = mloc % WOUT;
        abaseu[mt] = ((orow * STRIDE) * Wp + ocol * STRIDE + (1 - R)) * UPP + kgrp;
    }

    short8 af[3][MT], bf[3][NTW];
    f32x4 acc[MT][NTW] = {};

    auto readFrags = [&](int s, auto rIC) {
        constexpr int r = decltype(rIC)::value;
        int pos = s / KS, kk = s - (s / KS) * KS;
        int poff = ((pos / D) * Wp + (pos % D)) * UPP;
#pragma unroll
        for (int mt = 0; mt < MT; ++mt)
            af[r][mt] = ldsA[abaseu[mt] + poff + kk * 4];
        int slot = s % DEPTH;
#pragma unroll
        for (int nt = 0; nt < NTW; ++nt)
            bf[r][nt] = ldsB[((wid * DEPTH + slot) * NTW + nt) * 64 + su];
    };

    readFrags(0, ic<0>{});
    if (1 < NSTEP) readFrags(1, ic<1>{});

    unroll_all([&](auto sc) {
        constexpr int s = decltype(sc)::value;
        if constexpr (s + LA < NSTEP) issueChunk(s + LA, (s + LA) % DEPTH);
        if constexpr (s + 2 < NSTEP) {
            constexpr int I = (s + LA < NSTEP - 1) ? (s + LA) : (NSTEP - 1);
            constexpr int NW0 = (I - (s + 2)) * NTW;
            constexpr int NW = NW0 < 0 ? 0 : NW0;
            asm volatile("s_waitcnt vmcnt(%0)" :: "i"(NW) : "memory");
            readFrags(s + 2, ic<(s + 2) % 3>{});
        }
#pragma unroll
        for (int nt = 0; nt < NTW; ++nt)
#pragma unroll
            for (int mt = 0; mt < MT; ++mt)
                acc[mt][nt] = __builtin_amdgcn_mfma_f32_16x16x32_bf16(
                    af[s % 3][mt], bf[s % 3][nt], acc[mt][nt], 0, 0, 0);
    }, typename mkseq<NSTEP>::type{});

#pragma unroll
    for (int mt = 0; mt < MT; ++mt) {
#pragma unroll
        for (int nt = 0; nt < NTW; ++nt) {
            int cout = n0 + nt * 16 + col;
            float bv = bias[cout];
#pragma unroll
            for (int rg = 0; rg < 4; ++rg) {
                int mloc = mt * 16 + kgrp * 4 + rg;
                int orow = mloc / WOUT, ocol = mloc % WOUT;
                float v = fmaxf(acc[mt][nt][rg] + bv, 0.0f);
                out[((size_t)(b * Hpo + oh0 + orow + 1) * Wpo + ocol + 1) * COUT + cout] =
                    __float2bfloat16(v);
            }
        }
    }
}

// ---------------- conv_lds (register-ring) — used for conv8 (1x1, NSTEP=6) -------------
template <int CIN, int COUT, int HIN, int WIN, int STRIDE, int R,
          int WM, int WN, int MT, int NTW, int PW, int THREADS, int MINW>
__global__ __launch_bounds__(THREADS, MINW) void conv_lds(
    const __hip_bfloat16* __restrict__ in,
    const __hip_bfloat16* __restrict__ wt,
    const float* __restrict__ bias,
    __hip_bfloat16* __restrict__ out) {
    constexpr int HOUT = HIN / STRIDE, WOUT = WIN / STRIDE;
    constexpr int Hp = HIN + 2, Wp = WIN + 2;
    constexpr int Hpo = HOUT + 2, Wpo = WOUT + 2;
    constexpr int D = 2 * R + 1;
    constexpr int KS = CIN / 32;
    constexpr int NSTEP = D * D * KS;
    constexpr int BM = WM * MT * 16;
    constexpr int BN = WN * NTW * 16;
    static_assert(BN == COUT, "block covers full N");
    static_assert(BM % WOUT == 0, "block tile = whole output rows");
    static_assert(THREADS / 64 == WM * WN, "wave count");
    constexpr int BMR = BM / WOUT;
    constexpr int SUPR = (BMR - 1) * STRIDE + D;
    constexpr int CINU = CIN / 8;
    constexpr int UPP = CINU + 1;
    constexpr int ROWU = Wp * CINU;
    constexpr int TOTU = SUPR * ROWU;

    __shared__ short8 lds[SUPR * Wp * UPP];

    int m0 = blockIdx.x * BM;
    int gor = m0 / WOUT;
    int b = gor / HOUT;
    int oh0 = gor % HOUT;
    int r0 = oh0 * STRIDE + (1 - R);

    const __hip_bfloat16* gsrc = in + ((size_t)(b * Hp + r0) * Wp) * CIN;
    for (int g = threadIdx.x; g < TOTU; g += THREADS) {
        int row = g / ROWU;
        int ur = g - row * ROWU;
        int pix = ur / CINU;
        int c = ur - pix * CINU;
        lds[(row * Wp + pix) * UPP + c] = *reinterpret_cast<const short8*>(gsrc + (size_t)g * 8);
    }
    __syncthreads();

    int wid = threadIdx.x >> 6;
    int lane = threadIdx.x & 63;
    int col = lane & 15, kgrp = lane >> 4;
    int wm = wid / WN, wn = wid % WN;
    int n0 = wn * NTW * 16;

    int apix[MT];
#pragma unroll
    for (int mt = 0; mt < MT; ++mt) {
        int mloc = (wm * MT + mt) * 16 + col;
        int orow = mloc / WOUT, ocol = mloc % WOUT;
        apix[mt] = (orow * STRIDE) * Wp + ocol * STRIDE + (1 - R);
    }
    const __hip_bfloat16* bbase[NTW];
#pragma unroll
    for (int nt = 0; nt < NTW; ++nt)
        bbase[nt] = wt + (size_t)(n0 + nt * 16 + col) * 32 + kgrp * 8;

    short8 abuf[3][MT];
    short8 bbuf[PW][NTW];
    f32x4 acc[MT][NTW] = {};

    auto ldA = [&](int s, int slot) {
        int pos = s / KS, kk = s - (s / KS) * KS;
        int dh = pos / D, dw = pos - dh * D;
        int poff = dh * Wp + dw;
#pragma unroll
        for (int mt = 0; mt < MT; ++mt)
            abuf[slot][mt] = lds[(apix[mt] + poff) * UPP + kk * 4 + kgrp];
    };
    auto ldB = [&](int s, int slot) {
        size_t off = (size_t)s * (COUT * 32);
#pragma unroll
        for (int nt = 0; nt < NTW; ++nt)
            bbuf[slot][nt] = *reinterpret_cast<const short8*>(bbase[nt] + off);
    };

#pragma unroll
    for (int s = 0; s < PW - 1; ++s)
        if (s < NSTEP) ldB(s, s);
    ldA(0, 0);
    if (1 < NSTEP) ldA(1, 1);
    __builtin_amdgcn_sched_barrier(0);

#pragma unroll
    for (int s = 0; s < NSTEP; ++s) {
        if (s + PW - 1 < NSTEP) ldB(s + PW - 1, (s + PW - 1) % PW);
        if (s + 2 < NSTEP) ldA(s + 2, (s + 2) % 3);
        __builtin_amdgcn_sched_barrier(0);
#pragma unroll
        for (int nt = 0; nt < NTW; ++nt)
#pragma unroll
            for (int mt = 0; mt < MT; ++mt)
                acc[mt][nt] = __builtin_amdgcn_mfma_f32_16x16x32_bf16(
                    abuf[s % 3][mt], bbuf[s % PW][nt], acc[mt][nt], 0, 0, 0);
    }

#pragma unroll
    for (int mt = 0; mt < MT; ++mt) {
#pragma unroll
        for (int nt = 0; nt < NTW; ++nt) {
            int cout = n0 + nt * 16 + col;
            float bv = bias[cout];
#pragma unroll
            for (int rg = 0; rg < 4; ++rg) {
                int mloc = (wm * MT + mt) * 16 + kgrp * 4 + rg;
                int orow = mloc / WOUT, ocol = mloc % WOUT;
                float v = fmaxf(acc[mt][nt][rg] + bv, 0.0f);
                out[((size_t)(b * Hpo + oh0 + orow + 1) * Wpo + ocol + 1) * COUT + cout] =
                    __float2bfloat16(v);
            }
        }
    }
}

// ---------------- conv9: 1x1 192->10 (pad16), relu, fp32 NCHW-flat out [B][640] --------
__global__ __launch_bounds__(256) void conv9_kernel(
    const __hip_bfloat16* __restrict__ in, const __hip_bfloat16* __restrict__ wt,
    const float* __restrict__ bias, float* __restrict__ out) {
    int wid = threadIdx.x >> 6;
    int lane = threadIdx.x & 63;
    int wave = blockIdx.x * 4 + wid;
    int m0 = wave * 16;
    int col = lane & 15;
    int kgrp = lane >> 4;
    int m = m0 + col;
    int b = m >> 6; int r = m & 63; int oh = r >> 3; int ow = r & 7;
    const __hip_bfloat16* abase = in + ((size_t)(b * 10 + oh + 1) * 10 + ow + 1) * 192 + kgrp * 8;
    f32x4 acc = {};
#pragma unroll
    for (int kk = 0; kk < 6; ++kk) {
        short8 bfr = *reinterpret_cast<const short8*>(wt + ((size_t)kk * 16 + col) * 32 + kgrp * 8);
        short8 a = *reinterpret_cast<const short8*>(abase + kk * 32);
        acc = __builtin_amdgcn_mfma_f32_16x16x32_bf16(a, bfr, acc, 0, 0, 0);
    }
    if (col < 10) {
        float bv = bias[col];
#pragma unroll
        for (int rg = 0; rg < 4; ++rg) {
            int m2 = m0 + kgrp * 4 + rg;
            int b2 = m2 >> 6; int r2 = m2 & 63;
            out[(size_t)b2 * 640 + col * 64 + r2] = fmaxf(acc[rg] + bv, 0.0f);
        }
    }
}

// ---------------- fused head: fc1(640->100)+relu, fc2(100->10), encode -----------------
__global__ __launch_bounds__(128) void head_kernel(
    const float* __restrict__ act9, const float* __restrict__ fw1, const float* __restrict__ fb1,
    const float* __restrict__ fw2, const float* __restrict__ fb2,
    const int* __restrict__ p11, const float* __restrict__ s11, float* __restrict__ out) {
    __shared__ float x[640];
    __shared__ float h[100];
    __shared__ float o[10];
    int b = blockIdx.x, t = threadIdx.x;
    for (int i = t; i < 160; i += 128)
        ((float4*)x)[i] = ((const float4*)(act9 + (size_t)b * 640))[i];
    __syncthreads();
    if (t < 100) {
        float acc = fb1[t];
        const float4* wr = (const float4*)(fw1 + (size_t)t * 640);
        const float4* xv = (const float4*)x;
#pragma unroll 4
        for (int i = 0; i < 160; ++i) {
            float4 wv = wr[i], qv = xv[i];
            acc = fmaf(wv.x, qv.x, acc); acc = fmaf(wv.y, qv.y, acc);
            acc = fmaf(wv.z, qv.z, acc); acc = fmaf(wv.w, qv.w, acc);
        }
        h[t] = fmaxf(acc, 0.0f);
    }
    __syncthreads();
    if (t < 10) {
        float acc = fb2[t];
        for (int i = 0; i < 100; ++i) acc = fmaf(h[i], fw2[t * 100 + i], acc);
        o[t] = acc;
    }
    __syncthreads();
    if (t < 11) {
        int pi = p11[t];
        out[(size_t)b * 11 + t] = s11[t] * (pi == 10 ? 1.0f : o[pi]);
    }
}

extern "C" void kernel_launch(void* const* d_in, const int* in_sizes, int n_in,
                              void* d_out, int out_size, void* d_ws, size_t ws_size,
                              hipStream_t stream) {
    const int*   p0  = (const int*)  d_in[0];
    const float* s0  = (const float*)d_in[1];
    const int*   p11 = (const int*)  d_in[26];
    const float* s11 = (const float*)d_in[27];
    const float* w1 = (const float*)d_in[28]; const float* b1 = (const float*)d_in[29];
    const float* w2 = (const float*)d_in[30]; const float* b2 = (const float*)d_in[31];
    const float* w3 = (const float*)d_in[32]; const float* b3 = (const float*)d_in[33];
    const float* w4 = (const float*)d_in[34]; const float* b4 = (const float*)d_in[35];
    const float* w5 = (const float*)d_in[36]; const float* b5 = (const float*)d_in[37];
    const float* w6 = (const float*)d_in[38]; const float* b6 = (const float*)d_in[39];
    const float* w7 = (const float*)d_in[40]; const float* b7 = (const float*)d_in[41];
    const float* w8 = (const float*)d_in[42]; const float* b8 = (const float*)d_in[43];
    const float* w9 = (const float*)d_in[44]; const float* b9 = (const float*)d_in[45];
    const float* fw1 = (const float*)d_in[46]; const float* fb1 = (const float*)d_in[47];
    const float* fw2 = (const float*)d_in[48]; const float* fb2 = (const float*)d_in[49];
    const float* A0 = (const float*)d_in[50];
    float* out = (float*)d_out;

    // ---- workspace carve-up (256B aligned) ----
    size_t off = 0;
    auto alloc = [&](size_t bytes) {
        void* p = (char*)d_ws + off;
        off += (bytes + 255) & ~(size_t)255;
        return p;
    };
    const size_t SZ_3434_96  = (size_t)BATCH * 34 * 34 * 96 * 2;
    const size_t SZ_1818_96  = (size_t)BATCH * 18 * 18 * 96 * 2;
    const size_t SZ_1818_192 = (size_t)BATCH * 18 * 18 * 192 * 2;

    float* dec = (float*)alloc((size_t)BATCH * 34 * 34 * 4 * 4);
    __hip_bfloat16* regA = (__hip_bfloat16*)alloc(SZ_3434_96);   // act1; act5 [18,18,192]
    __hip_bfloat16* regB = (__hip_bfloat16*)alloc(SZ_3434_96);   // act2; act8 [10,10,192]
    __hip_bfloat16* regC = (__hip_bfloat16*)alloc(SZ_1818_96);   // act3; act6 [10,10,192]
    __hip_bfloat16* regD = (__hip_bfloat16*)alloc(SZ_1818_192);  // act4; act7 [10,10,192]
    __hip_bfloat16* wt2 = (__hip_bfloat16*)alloc((size_t)9 * 96 * 96 * 2);
    __hip_bfloat16* wt3 = (__hip_bfloat16*)alloc((size_t)9 * 96 * 96 * 2);
    __hip_bfloat16* wt4 = (__hip_bfloat16*)alloc((size_t)9 * 192 * 96 * 2);
    __hip_bfloat16* wt5 = (__hip_bfloat16*)alloc((size_t)9 * 192 * 192 * 2);
    __hip_bfloat16* wt6 = (__hip_bfloat16*)alloc((size_t)9 * 192 * 192 * 2);
    __hip_bfloat16* wt7 = (__hip_bfloat16*)alloc((size_t)9 * 192 * 192 * 2);
    __hip_bfloat16* wt8 = (__hip_bfloat16*)alloc((size_t)1 * 192 * 192 * 2);
    __hip_bfloat16* wt9 = (__hip_bfloat16*)alloc((size_t)16 * 192 * 2);
    float* act9 = (float*)alloc((size_t)BATCH * 640 * 4);

    const int TPB = 256;

    // decode input
    int decN = BATCH * 34 * 34 * 4;
    fill0_f32<<<CDIV(decN, TPB), TPB, 0, stream>>>(dec, decN);
    decode_kernel<<<CDIV(BATCH * 3073, TPB), TPB, 0, stream>>>(A0, p0, s0, dec);

    // fused weight transform (k-chunk-contiguous layout)
    Wt8 wts;
    wts.s[0] = {w2, wt2, 96, 96, 9, 96};
    wts.s[1] = {w3, wt3, 96, 96, 9, 96};
    wts.s[2] = {w4, wt4, 192, 96, 9, 192};
    wts.s[3] = {w5, wt5, 192, 192, 9, 192};
    wts.s[4] = {w6, wt6, 192, 192, 9, 192};
    wts.s[5] = {w7, wt7, 192, 192, 9, 192};
    wts.s[6] = {w8, wt8, 192, 192, 1, 192};
    wts.s[7] = {w9, wt9, 10, 192, 1, 16};
    wts.cum[0] = 0;
    for (int i = 0; i < 8; ++i)
        wts.cum[i + 1] = wts.cum[i] + wts.s[i].KK * wts.s[i].CoutPad * wts.s[i].Cin;
    wt_transform_multi<<<CDIV(wts.cum[8], TPB), TPB, 0, stream>>>(wts);

    // fused halo zero: act1, act2, act3, act4
    auto chunks = [](int Hp, int Wp, int C) { return BATCH * (2 * Wp + 2 * (Hp - 2)) * C / 8; };
    Halo4 h0;
    h0.d[0] = {regA, 34, 34, 96};
    h0.d[1] = {regB, 34, 34, 96};
    h0.d[2] = {regC, 18, 18, 96};
    h0.d[3] = {regD, 18, 18, 192};
    h0.n = 4; h0.cum[0] = 0;
    for (int i = 0; i < 4; ++i)
        h0.cum[i + 1] = h0.cum[i] + chunks(h0.d[i].Hp, h0.d[i].Wp, h0.d[i].C);
    halo_zero_multi<<<CDIV(h0.cum[4], TPB), TPB, 0, stream>>>(h0);

    // conv1: dec -> act1 (regA)
    conv1_kernel<<<2048, 256, 0, stream>>>(dec, w1, b1, regA);
    // conv2: act1 -> act2 (regB)   BM=128 (WM4,WN2,MT2,NTW3), 512t -> 16 waves/CU, grid 1024
    conv_2ph<96, 96, 32, 32, 1, 1, 4, 2, 2, 3, 512, 4><<<1024, 512, 0, stream>>>(regA, wt2, b2, regB);
    // conv3 (s2): act2 -> act3 (regC)   BM=64 (WM2,WN2,MT2,NTW3), 256t, grid 512
    conv_2ph<96, 96, 32, 32, 2, 1, 2, 2, 2, 3, 256, 2><<<512, 256, 0, stream>>>(regB, wt3, b3, regC);
    // conv4: act3 -> act4 (regD)   BM=64 (WM2,WN4,MT2,NTW3), 512t -> 16 waves/CU, grid 512
    conv_2ph<96, 192, 16, 16, 1, 1, 2, 4, 2, 3, 512, 4><<<512, 512, 0, stream>>>(regC, wt4, b4, regD);
    // merged halo re-zero: act5 (regA, free after conv2) + act6 (regC, free after conv4)
    Halo4 h56;
    h56.d[0] = {regA, 18, 18, 192};
    h56.d[1] = {regC, 10, 10, 192};
    h56.n = 2; h56.cum[0] = 0;
    h56.cum[1] = chunks(18, 18, 192);
    h56.cum[2] = h56.cum[1] + chunks(10, 10, 192);
    halo_zero_multi<<<CDIV(h56.cum[2], TPB), TPB, 0, stream>>>(h56);
    // conv5: act4 -> act5 (regA)   BM=64 (WM2,WN4,MT2,NTW3), 512t, grid 512, NSTEP=54
    conv_2ph<192, 192, 16, 16, 1, 1, 2, 4, 2, 3, 512, 4><<<512, 512, 0, stream>>>(regD, wt5, b5, regA);
    // conv6 (s2): act5 -> act6 (regC)   conv_pipe (small M)
    conv_pipe<192, 192, 16, 16, 2, 1, 4, 1, 3, 3, 3, 256, 2><<<512, 256, 0, stream>>>(regA, wt6, b6, regC);
    // conv7: act6 -> act7 (regD)   conv_pipe
    conv_pipe<192, 192, 8, 8, 1, 1, 4, 2, 3, 4, 4, 256, 2><<<256, 256, 0, stream>>>(regC, wt7, b7, regD);
    // conv8 (1x1): act7 -> act8 (regB)   register-ring kernel
    conv_lds<192, 192, 8, 8, 1, 0, 1, 4, 1, 3, 6, 256, 3><<<512, 256, 0, stream>>>(regD, wt8, b8, regB);
    // conv9 (1x1 192->10): act8 -> act9 fp32
    conv9_kernel<<<128, 256, 0, stream>>>(regB, wt9, b9, act9);
    // fused fc1+fc2+encode
    head_kernel<<<BATCH, 128, 0, stream>>>(act9, fw1, fb1, fw2, fb2, p11, s11, out);
}

// Round 21
// 185.901 us; speedup vs baseline: 1.2274x; 1.0187x over previous
//
#include <hip/hip_runtime.h>
#include <hip/hip_bf16.h>

#define BATCH 128
#define CDIV(a, b) (((a) + (b) - 1) / (b))

typedef __attribute__((ext_vector_type(8))) short short8;
typedef __attribute__((ext_vector_type(4))) float f32x4;

// compile-time unroll helpers
template <int V> struct ic { static constexpr int value = V; };
template <int... I> struct iseq {};
template <int N, int... I> struct mkseq : mkseq<N - 1, N - 1, I...> {};
template <int... I> struct mkseq<0, I...> { using type = iseq<I...>; };
template <class F, int... I>
__device__ __forceinline__ void unroll_all(F&& f, iseq<I...>) { (f(ic<I>{}), ...); }

// async global->LDS 16B: LDS dest = wave-uniform base + lane*16; global source per-lane
__device__ __forceinline__ void gload_lds16(const void* g, void* l) {
    __builtin_amdgcn_global_load_lds(
        (const __attribute__((address_space(1))) void*)g,
        (__attribute__((address_space(3))) void*)l, 16, 0, 0);
}

// 16B-unit swizzle sigma(u) = u ^ ((u>>2)&7) (bank spread for stride-4-unit frag reads)
__device__ __forceinline__ int sig_u(int u) { return u ^ ((u >> 2) & 7); }
__device__ __forceinline__ int inv_sig_u(int x) {
    int r0 = ((x >> 2) ^ (x >> 4)) & 1;
    int r1 = (x >> 3) & 1;
    int r2 = (x >> 4) & 1;
    return x ^ (r0 | (r1 << 1) | (r2 << 2));
}

// ---------------- zero fill (f32) ----------------
__global__ void fill0_f32(float* __restrict__ p, int n) {
    int i = blockIdx.x * blockDim.x + threadIdx.x;
    if (i < n) p[i] = 0.0f;
}

// ---------------- decode: scatter A0 -> padded NHWC f32 [B][34][34][4] ----------------
__global__ void decode_kernel(const float* __restrict__ y, const int* __restrict__ p,
                              const float* __restrict__ s, float* __restrict__ x) {
    const int n = 3073;
    int idx = blockIdx.x * blockDim.x + threadIdx.x;
    if (idx >= BATCH * n) return;
    int i = idx % n, b = idx / n;
    int pi = p[i];
    if (pi >= 3072) return;
    float v = y[(size_t)b * n + i] / s[i];
    int c = pi >> 10; int r = pi & 1023; int h = r >> 5; int w = r & 31;
    x[((size_t)(b * 34 + h + 1) * 34 + (w + 1)) * 4 + c] = v;
}

// ---------------- fused halo zero (up to 4 padded bf16 NHWC buffers) ----------------
struct HaloDesc { __hip_bfloat16* p; int Hp, Wp, C; };
struct Halo4 { HaloDesc d[4]; int cum[5]; int n; };

__global__ void halo_zero_multi(Halo4 h) {
    int idx = blockIdx.x * 256 + threadIdx.x;
    if (idx >= h.cum[h.n]) return;
    int seg = 0;
    while (idx >= h.cum[seg + 1]) ++seg;
    int local = idx - h.cum[seg];
    HaloDesc d = h.d[seg];
    int perB = (2 * d.Wp + 2 * (d.Hp - 2)) * d.C / 8;
    int b = local / perB;
    int r = (local % perB) * 8;
    int WpC = d.Wp * d.C;
    long addr;
    if (r < WpC) {
        addr = (long)(b * d.Hp) * WpC + r;
    } else if (r < 2 * WpC) {
        addr = (long)(b * d.Hp + d.Hp - 1) * WpC + (r - WpC);
    } else {
        int r3 = r - 2 * WpC;
        int sideN = (d.Hp - 2) * d.C;
        int side = r3 / sideN;
        int r4 = r3 % sideN;
        int row = 1 + r4 / d.C, c = r4 % d.C;
        addr = ((long)(b * d.Hp + row) * d.Wp + (side ? d.Wp - 1 : 0)) * d.C + c;
    }
    *(uint4*)((char*)d.p + addr * 2) = uint4{0, 0, 0, 0};
}

// ------ fused weight transform: OIHW f32 -> [pos*KS+kk][CoutPad][32] bf16 (k-chunked) ---
struct WtSeg { const float* src; __hip_bfloat16* dst; int Cout, Cin, KK, CoutPad; };
struct Wt8 { WtSeg s[8]; int cum[9]; };

__global__ void wt_transform_multi(Wt8 w) {
    int idx = blockIdx.x * 256 + threadIdx.x;
    if (idx >= w.cum[8]) return;
    int seg = 0;
    while (idx >= w.cum[seg + 1]) ++seg;
    int local = idx - w.cum[seg];
    WtSeg sg = w.s[seg];
    int c2 = local % 32; int t = local / 32;
    int co = t % sg.CoutPad; int t2 = t / sg.CoutPad;   // t2 = pos*KS + kk
    int KS = sg.Cin / 32;
    int kk = t2 % KS; int pos = t2 / KS;
    int cin = kk * 32 + c2;
    float v = (co < sg.Cout) ? sg.src[((size_t)co * sg.Cin + cin) * sg.KK + pos] : 0.0f;
    sg.dst[local] = __float2bfloat16(v);
}

// ---------------- conv1: 3->96 @32x32, fp32, 4 threads/pixel, packed stores ------------
__global__ __launch_bounds__(256) void conv1_kernel(
    const float* __restrict__ in, const float* __restrict__ w,
    const float* __restrict__ bias, __hip_bfloat16* __restrict__ out) {
    __shared__ float ws[96 * 27];
    __shared__ float bs[96];
    for (int i = threadIdx.x; i < 96 * 27; i += 256) ws[i] = w[i];
    if (threadIdx.x < 96) bs[threadIdx.x] = bias[threadIdx.x];
    __syncthreads();
    int idx = blockIdx.x * 256 + threadIdx.x;
    int q = idx & 3; int pix = idx >> 2;
    int b = pix >> 10, r = pix & 1023, oh = r >> 5, ow = r & 31;
    const float* ib = in + ((size_t)(b * 34 + oh) * 34 + ow) * 4;
    float patch[9][3];
#pragma unroll
    for (int ph = 0; ph < 3; ++ph)
#pragma unroll
        for (int pw = 0; pw < 3; ++pw) {
            float4 v = *(const float4*)(ib + ((size_t)ph * 34 + pw) * 4);
            patch[ph * 3 + pw][0] = v.x; patch[ph * 3 + pw][1] = v.y; patch[ph * 3 + pw][2] = v.z;
        }
    const int c0 = q * 24;
    float acc[24];
#pragma unroll
    for (int j = 0; j < 24; ++j) acc[j] = bs[c0 + j];
    for (int j = 0; j < 24; ++j) {
        const float* wc = &ws[(c0 + j) * 27];
#pragma unroll
        for (int ci = 0; ci < 3; ++ci)
#pragma unroll
            for (int pos = 0; pos < 9; ++pos)
                acc[j] = fmaf(patch[pos][ci], wc[ci * 9 + pos], acc[j]);
    }
    __hip_bfloat16* ob = out + ((size_t)(b * 34 + oh + 1) * 34 + ow + 1) * 96 + c0;
#pragma unroll
    for (int g = 0; g < 3; ++g) {
        union { uint4 u; unsigned short s[8]; } pk;
#pragma unroll
        for (int e = 0; e < 8; ++e) {
            __hip_bfloat16 hv = __float2bfloat16(fmaxf(acc[g * 8 + e], 0.0f));
            pk.s[e] = *(unsigned short*)&hv;
        }
        *(uint4*)(ob + g * 8) = pk.u;
    }
}

// ======== conv_2ph: shared LDS chunk ring + counted vmcnt + RAW barrier, WMxWN waves ====
// LA=2, DEPTH=4 (race-free: DEPTH >= LA+2). 512-thread variants (8 waves) double
// waves/CU at identical LDS footprint (LDS is the binding resource, not threads).
template <int CIN, int COUT, int HIN, int WIN, int STRIDE, int R,
          int WM, int WN, int MT, int NTW, int THREADS, int MINW>
__global__ __launch_bounds__(THREADS, MINW) void conv_2ph(
    const __hip_bfloat16* __restrict__ in,   // [B][HIN+2][WIN+2][CIN]
    const __hip_bfloat16* __restrict__ wt,   // [(2R+1)^2*KS][COUT][32]
    const float* __restrict__ bias,
    __hip_bfloat16* __restrict__ out) {      // [B][HOUT+2][WOUT+2][COUT]
    constexpr int HOUT = HIN / STRIDE, WOUT = WIN / STRIDE;
    constexpr int Hp = HIN + 2, Wp = WIN + 2;
    constexpr int Hpo = HOUT + 2, Wpo = WOUT + 2;
    constexpr int D = 2 * R + 1;
    constexpr int KS = CIN / 32;
    constexpr int NSTEP = D * D * KS;
    constexpr int WAVES = THREADS / 64;
    static_assert(WAVES == WM * WN, "wave grid");
    constexpr int BMPIX = WM * MT * 16;
    static_assert(WN * NTW * 16 == COUT, "N covers COUT");
    constexpr int AUN = BMPIX * 4;           // A 16B-units per chunk
    constexpr int BUN = COUT * 4;            // B 16B-units per chunk
    constexpr int CUN = AUN + BUN;
    constexpr int DEPTH = 4, LA = 2;         // DEPTH >= LA+2 (race-free ring)
    constexpr int LPW = CDIV(CUN, 64 * WAVES);
    constexpr int CUN_ALLOC = LPW * 64 * WAVES;   // incl. scratch tail for dummy loads

    __shared__ short8 lds[DEPTH * CUN_ALLOC];

    int wid = threadIdx.x >> 6;
    int lane = threadIdx.x & 63;
    int col = lane & 15, kgrp = lane >> 4;
    int wm = wid / WN, wn = wid % WN;
    int n0 = wn * (NTW * 16);
    int mBase = wm * (MT * 16);

    // ---- per-lane stage descriptors (source pre-inverse-swizzled) ----
    const __hip_bfloat16* aSrc[LPW];
    int bOff[LPW];
    bool isA[LPW];
#pragma unroll
    for (int i = 0; i < LPW; ++i) {
        int x = (wid * LPW + i) * 64 + lane;     // LDS unit within (padded) chunk
        if (x < AUN) {
            isA[i] = true;
            int v = inv_sig_u(x);
            int p = v >> 2, q = v & 3;
            int gp = blockIdx.x * BMPIX + p;
            int b = gp / (HOUT * WOUT);
            int r = gp % (HOUT * WOUT);
            int oh = r / WOUT, ow = r % WOUT;
            aSrc[i] = in + ((size_t)(b * Hp + oh * STRIDE + 1 - R) * Wp
                            + ow * STRIDE + 1 - R) * CIN + q * 8;
            bOff[i] = 0;
        } else {
            isA[i] = false;
            // units in [AUN, CUN): real B; units >= CUN: dummy (read chunk start)
            bOff[i] = (x < CUN) ? inv_sig_u(x - AUN) * 8 : 0;
            aSrc[i] = in;
        }
    }
    // ---- frag read offsets (swizzled, within chunk) ----
    int aRd[MT], bRd[NTW];
#pragma unroll
    for (int mt = 0; mt < MT; ++mt)
        aRd[mt] = sig_u((mBase + mt * 16 + col) * 4 + kgrp);
#pragma unroll
    for (int nt = 0; nt < NTW; ++nt)
        bRd[nt] = AUN + sig_u((n0 + nt * 16 + col) * 4 + kgrp);

    auto stepAoff = [](int s) {
        int pos = s / KS, kk = s - (s / KS) * KS;
        return ((pos / D) * Wp + (pos % D)) * CIN + kk * 32;
    };
    auto stage = [&](int s) {
        int slot = s % DEPTH;
        int aoff = stepAoff(s);
        const __hip_bfloat16* wchunk = wt + (size_t)s * (COUT * 32);
#pragma unroll
        for (int i = 0; i < LPW; ++i) {
            const __hip_bfloat16* src = isA[i] ? (aSrc[i] + aoff) : (wchunk + bOff[i]);
            gload_lds16(src, &lds[slot * CUN_ALLOC + (wid * LPW + i) * 64]);
        }
    };

    f32x4 acc[MT][NTW] = {};
    stage(0);
    if constexpr (1 < NSTEP) stage(1);

    unroll_all([&](auto sc) {
        constexpr int s = decltype(sc)::value;
        if constexpr (s + LA < NSTEP) stage(s + LA);
        constexpr int C = (s + 1 < NSTEP ? 1 : 0) + (s + 2 < NSTEP ? 1 : 0);
        asm volatile("s_waitcnt vmcnt(%0)" :: "i"(C * LPW) : "memory");
        __builtin_amdgcn_s_barrier();            // raw rendezvous, no drain
        __builtin_amdgcn_sched_barrier(0);
        constexpr int slot = s % DEPTH;
        short8 af[MT], bfr[NTW];
#pragma unroll
        for (int mt = 0; mt < MT; ++mt) af[mt] = lds[slot * CUN_ALLOC + aRd[mt]];
#pragma unroll
        for (int nt = 0; nt < NTW; ++nt) bfr[nt] = lds[slot * CUN_ALLOC + bRd[nt]];
#pragma unroll
        for (int nt = 0; nt < NTW; ++nt)
#pragma unroll
            for (int mt = 0; mt < MT; ++mt)
                acc[mt][nt] = __builtin_amdgcn_mfma_f32_16x16x32_bf16(
                    af[mt], bfr[nt], acc[mt][nt], 0, 0, 0);
    }, typename mkseq<NSTEP>::type{});

    // epilogue: bias + relu + bf16 store into padded NHWC
#pragma unroll
    for (int mt = 0; mt < MT; ++mt) {
#pragma unroll
        for (int nt = 0; nt < NTW; ++nt) {
            int cout = n0 + nt * 16 + col;
            float bv = bias[cout];
#pragma unroll
            for (int rg = 0; rg < 4; ++rg) {
                int p = mBase + mt * 16 + kgrp * 4 + rg;
                int gp = blockIdx.x * BMPIX + p;
                int b = gp / (HOUT * WOUT);
                int r = gp % (HOUT * WOUT);
                int oh = r / WOUT, ow = r % WOUT;
                float v = fmaxf(acc[mt][nt][rg] + bv, 0.0f);
                out[((size_t)(b * Hpo + oh + 1) * Wpo + ow + 1) * COUT + cout] =
                    __float2bfloat16(v);
            }
        }
    }
}

// ---------------- conv_lds (register-ring) — used for conv8 (1x1, NSTEP=6) -------------
template <int CIN, int COUT, int HIN, int WIN, int STRIDE, int R,
          int WM, int WN, int MT, int NTW, int PW, int THREADS, int MINW>
__global__ __launch_bounds__(THREADS, MINW) void conv_lds(
    const __hip_bfloat16* __restrict__ in,
    const __hip_bfloat16* __restrict__ wt,
    const float* __restrict__ bias,
    __hip_bfloat16* __restrict__ out) {
    constexpr int HOUT = HIN / STRIDE, WOUT = WIN / STRIDE;
    constexpr int Hp = HIN + 2, Wp = WIN + 2;
    constexpr int Hpo = HOUT + 2, Wpo = WOUT + 2;
    constexpr int D = 2 * R + 1;
    constexpr int KS = CIN / 32;
    constexpr int NSTEP = D * D * KS;
    constexpr int BM = WM * MT * 16;
    constexpr int BN = WN * NTW * 16;
    static_assert(BN == COUT, "block covers full N");
    static_assert(BM % WOUT == 0, "block tile = whole output rows");
    static_assert(THREADS / 64 == WM * WN, "wave count");
    constexpr int BMR = BM / WOUT;
    constexpr int SUPR = (BMR - 1) * STRIDE + D;
    constexpr int CINU = CIN / 8;
    constexpr int UPP = CINU + 1;
    constexpr int ROWU = Wp * CINU;
    constexpr int TOTU = SUPR * ROWU;

    __shared__ short8 lds[SUPR * Wp * UPP];

    int m0 = blockIdx.x * BM;
    int gor = m0 / WOUT;
    int b = gor / HOUT;
    int oh0 = gor % HOUT;
    int r0 = oh0 * STRIDE + (1 - R);

    const __hip_bfloat16* gsrc = in + ((size_t)(b * Hp + r0) * Wp) * CIN;
    for (int g = threadIdx.x; g < TOTU; g += THREADS) {
        int row = g / ROWU;
        int ur = g - row * ROWU;
        int pix = ur / CINU;
        int c = ur - pix * CINU;
        lds[(row * Wp + pix) * UPP + c] = *reinterpret_cast<const short8*>(gsrc + (size_t)g * 8);
    }
    __syncthreads();

    int wid = threadIdx.x >> 6;
    int lane = threadIdx.x & 63;
    int col = lane & 15, kgrp = lane >> 4;
    int wm = wid / WN, wn = wid % WN;
    int n0 = wn * NTW * 16;

    int apix[MT];
#pragma unroll
    for (int mt = 0; mt < MT; ++mt) {
        int mloc = (wm * MT + mt) * 16 + col;
        int orow = mloc / WOUT, ocol = mloc % WOUT;
        apix[mt] = (orow * STRIDE) * Wp + ocol * STRIDE + (1 - R);
    }
    const __hip_bfloat16* bbase[NTW];
#pragma unroll
    for (int nt = 0; nt < NTW; ++nt)
        bbase[nt] = wt + (size_t)(n0 + nt * 16 + col) * 32 + kgrp * 8;

    short8 abuf[3][MT];
    short8 bbuf[PW][NTW];
    f32x4 acc[MT][NTW] = {};

    auto ldA = [&](int s, int slot) {
        int pos = s / KS, kk = s - (s / KS) * KS;
        int dh = pos / D, dw = pos - dh * D;
        int poff = dh * Wp + dw;
#pragma unroll
        for (int mt = 0; mt < MT; ++mt)
            abuf[slot][mt] = lds[(apix[mt] + poff) * UPP + kk * 4 + kgrp];
    };
    auto ldB = [&](int s, int slot) {
        size_t off = (size_t)s * (COUT * 32);
#pragma unroll
        for (int nt = 0; nt < NTW; ++nt)
            bbuf[slot][nt] = *reinterpret_cast<const short8*>(bbase[nt] + off);
    };

#pragma unroll
    for (int s = 0; s < PW - 1; ++s)
        if (s < NSTEP) ldB(s, s);
    ldA(0, 0);
    if (1 < NSTEP) ldA(1, 1);
    __builtin_amdgcn_sched_barrier(0);

#pragma unroll
    for (int s = 0; s < NSTEP; ++s) {
        if (s + PW - 1 < NSTEP) ldB(s + PW - 1, (s + PW - 1) % PW);
        if (s + 2 < NSTEP) ldA(s + 2, (s + 2) % 3);
        __builtin_amdgcn_sched_barrier(0);
#pragma unroll
        for (int nt = 0; nt < NTW; ++nt)
#pragma unroll
            for (int mt = 0; mt < MT; ++mt)
                acc[mt][nt] = __builtin_amdgcn_mfma_f32_16x16x32_bf16(
                    abuf[s % 3][mt], bbuf[s % PW][nt], acc[mt][nt], 0, 0, 0);
    }

#pragma unroll
    for (int mt = 0; mt < MT; ++mt) {
#pragma unroll
        for (int nt = 0; nt < NTW; ++nt) {
            int cout = n0 + nt * 16 + col;
            float bv = bias[cout];
#pragma unroll
            for (int rg = 0; rg < 4; ++rg) {
                int mloc = (wm * MT + mt) * 16 + kgrp * 4 + rg;
                int orow = mloc / WOUT, ocol = mloc % WOUT;
                float v = fmaxf(acc[mt][nt][rg] + bv, 0.0f);
                out[((size_t)(b * Hpo + oh0 + orow + 1) * Wpo + ocol + 1) * COUT + cout] =
                    __float2bfloat16(v);
            }
        }
    }
}

// ---------------- conv9: 1x1 192->10 (pad16), relu, fp32 NCHW-flat out [B][640] --------
__global__ __launch_bounds__(256) void conv9_kernel(
    const __hip_bfloat16* __restrict__ in, const __hip_bfloat16* __restrict__ wt,
    const float* __restrict__ bias, float* __restrict__ out) {
    int wid = threadIdx.x >> 6;
    int lane = threadIdx.x & 63;
    int wave = blockIdx.x * 4 + wid;
    int m0 = wave * 16;
    int col = lane & 15;
    int kgrp = lane >> 4;
    int m = m0 + col;
    int b = m >> 6; int r = m & 63; int oh = r >> 3; int ow = r & 7;
    const __hip_bfloat16* abase = in + ((size_t)(b * 10 + oh + 1) * 10 + ow + 1) * 192 + kgrp * 8;
    f32x4 acc = {};
#pragma unroll
    for (int kk = 0; kk < 6; ++kk) {
        short8 bfr = *reinterpret_cast<const short8*>(wt + ((size_t)kk * 16 + col) * 32 + kgrp * 8);
        short8 a = *reinterpret_cast<const short8*>(abase + kk * 32);
        acc = __builtin_amdgcn_mfma_f32_16x16x32_bf16(a, bfr, acc, 0, 0, 0);
    }
    if (col < 10) {
        float bv = bias[col];
#pragma unroll
        for (int rg = 0; rg < 4; ++rg) {
            int m2 = m0 + kgrp * 4 + rg;
            int b2 = m2 >> 6; int r2 = m2 & 63;
            out[(size_t)b2 * 640 + col * 64 + r2] = fmaxf(acc[rg] + bv, 0.0f);
        }
    }
}

// ---------------- fused head: fc1(640->100)+relu, fc2(100->10), encode -----------------
__global__ __launch_bounds__(128) void head_kernel(
    const float* __restrict__ act9, const float* __restrict__ fw1, const float* __restrict__ fb1,
    const float* __restrict__ fw2, const float* __restrict__ fb2,
    const int* __restrict__ p11, const float* __restrict__ s11, float* __restrict__ out) {
    __shared__ float x[640];
    __shared__ float h[100];
    __shared__ float o[10];
    int b = blockIdx.x, t = threadIdx.x;
    for (int i = t; i < 160; i += 128)
        ((float4*)x)[i] = ((const float4*)(act9 + (size_t)b * 640))[i];
    __syncthreads();
    if (t < 100) {
        float acc = fb1[t];
        const float4* wr = (const float4*)(fw1 + (size_t)t * 640);
        const float4* xv = (const float4*)x;
#pragma unroll 4
        for (int i = 0; i < 160; ++i) {
            float4 wv = wr[i], qv = xv[i];
            acc = fmaf(wv.x, qv.x, acc); acc = fmaf(wv.y, qv.y, acc);
            acc = fmaf(wv.z, qv.z, acc); acc = fmaf(wv.w, qv.w, acc);
        }
        h[t] = fmaxf(acc, 0.0f);
    }
    __syncthreads();
    if (t < 10) {
        float acc = fb2[t];
        for (int i = 0; i < 100; ++i) acc = fmaf(h[i], fw2[t * 100 + i], acc);
        o[t] = acc;
    }
    __syncthreads();
    if (t < 11) {
        int pi = p11[t];
        out[(size_t)b * 11 + t] = s11[t] * (pi == 10 ? 1.0f : o[pi]);
    }
}

extern "C" void kernel_launch(void* const* d_in, const int* in_sizes, int n_in,
                              void* d_out, int out_size, void* d_ws, size_t ws_size,
                              hipStream_t stream) {
    const int*   p0  = (const int*)  d_in[0];
    const float* s0  = (const float*)d_in[1];
    const int*   p11 = (const int*)  d_in[26];
    const float* s11 = (const float*)d_in[27];
    const float* w1 = (const float*)d_in[28]; const float* b1 = (const float*)d_in[29];
    const float* w2 = (const float*)d_in[30]; const float* b2 = (const float*)d_in[31];
    const float* w3 = (const float*)d_in[32]; const float* b3 = (const float*)d_in[33];
    const float* w4 = (const float*)d_in[34]; const float* b4 = (const float*)d_in[35];
    const float* w5 = (const float*)d_in[36]; const float* b5 = (const float*)d_in[37];
    const float* w6 = (const float*)d_in[38]; const float* b6 = (const float*)d_in[39];
    const float* w7 = (const float*)d_in[40]; const float* b7 = (const float*)d_in[41];
    const float* w8 = (const float*)d_in[42]; const float* b8 = (const float*)d_in[43];
    const float* w9 = (const float*)d_in[44]; const float* b9 = (const float*)d_in[45];
    const float* fw1 = (const float*)d_in[46]; const float* fb1 = (const float*)d_in[47];
    const float* fw2 = (const float*)d_in[48]; const float* fb2 = (const float*)d_in[49];
    const float* A0 = (const float*)d_in[50];
    float* out = (float*)d_out;

    // ---- workspace carve-up (256B aligned) ----
    size_t off = 0;
    auto alloc = [&](size_t bytes) {
        void* p = (char*)d_ws + off;
        off += (bytes + 255) & ~(size_t)255;
        return p;
    };
    const size_t SZ_3434_96  = (size_t)BATCH * 34 * 34 * 96 * 2;
    const size_t SZ_1818_96  = (size_t)BATCH * 18 * 18 * 96 * 2;
    const size_t SZ_1818_192 = (size_t)BATCH * 18 * 18 * 192 * 2;

    float* dec = (float*)alloc((size_t)BATCH * 34 * 34 * 4 * 4);
    __hip_bfloat16* regA = (__hip_bfloat16*)alloc(SZ_3434_96);   // act1; act5 [18,18,192]
    __hip_bfloat16* regB = (__hip_bfloat16*)alloc(SZ_3434_96);   // act2; act8 [10,10,192]
    __hip_bfloat16* regC = (__hip_bfloat16*)alloc(SZ_1818_96);   // act3; act6 [10,10,192]
    __hip_bfloat16* regD = (__hip_bfloat16*)alloc(SZ_1818_192);  // act4; act7 [10,10,192]
    __hip_bfloat16* wt2 = (__hip_bfloat16*)alloc((size_t)9 * 96 * 96 * 2);
    __hip_bfloat16* wt3 = (__hip_bfloat16*)alloc((size_t)9 * 96 * 96 * 2);
    __hip_bfloat16* wt4 = (__hip_bfloat16*)alloc((size_t)9 * 192 * 96 * 2);
    __hip_bfloat16* wt5 = (__hip_bfloat16*)alloc((size_t)9 * 192 * 192 * 2);
    __hip_bfloat16* wt6 = (__hip_bfloat16*)alloc((size_t)9 * 192 * 192 * 2);
    __hip_bfloat16* wt7 = (__hip_bfloat16*)alloc((size_t)9 * 192 * 192 * 2);
    __hip_bfloat16* wt8 = (__hip_bfloat16*)alloc((size_t)1 * 192 * 192 * 2);
    __hip_bfloat16* wt9 = (__hip_bfloat16*)alloc((size_t)16 * 192 * 2);
    float* act9 = (float*)alloc((size_t)BATCH * 640 * 4);

    const int TPB = 256;

    // decode input
    int decN = BATCH * 34 * 34 * 4;
    fill0_f32<<<CDIV(decN, TPB), TPB, 0, stream>>>(dec, decN);
    decode_kernel<<<CDIV(BATCH * 3073, TPB), TPB, 0, stream>>>(A0, p0, s0, dec);

    // fused weight transform (k-chunk-contiguous layout)
    Wt8 wts;
    wts.s[0] = {w2, wt2, 96, 96, 9, 96};
    wts.s[1] = {w3, wt3, 96, 96, 9, 96};
    wts.s[2] = {w4, wt4, 192, 96, 9, 192};
    wts.s[3] = {w5, wt5, 192, 192, 9, 192};
    wts.s[4] = {w6, wt6, 192, 192, 9, 192};
    wts.s[5] = {w7, wt7, 192, 192, 9, 192};
    wts.s[6] = {w8, wt8, 192, 192, 1, 192};
    wts.s[7] = {w9, wt9, 10, 192, 1, 16};
    wts.cum[0] = 0;
    for (int i = 0; i < 8; ++i)
        wts.cum[i + 1] = wts.cum[i] + wts.s[i].KK * wts.s[i].CoutPad * wts.s[i].Cin;
    wt_transform_multi<<<CDIV(wts.cum[8], TPB), TPB, 0, stream>>>(wts);

    // fused halo zero: act1, act2, act3, act4
    auto chunks = [](int Hp, int Wp, int C) { return BATCH * (2 * Wp + 2 * (Hp - 2)) * C / 8; };
    Halo4 h0;
    h0.d[0] = {regA, 34, 34, 96};
    h0.d[1] = {regB, 34, 34, 96};
    h0.d[2] = {regC, 18, 18, 96};
    h0.d[3] = {regD, 18, 18, 192};
    h0.n = 4; h0.cum[0] = 0;
    for (int i = 0; i < 4; ++i)
        h0.cum[i + 1] = h0.cum[i] + chunks(h0.d[i].Hp, h0.d[i].Wp, h0.d[i].C);
    halo_zero_multi<<<CDIV(h0.cum[4], TPB), TPB, 0, stream>>>(h0);

    // conv1: dec -> act1 (regA)
    conv1_kernel<<<2048, 256, 0, stream>>>(dec, w1, b1, regA);
    // conv2: act1 -> act2 (regB)   BM=128 (WM4,WN2,MT2,NTW3), 512t -> 16 waves/CU, grid 1024
    conv_2ph<96, 96, 32, 32, 1, 1, 4, 2, 2, 3, 512, 4><<<1024, 512, 0, stream>>>(regA, wt2, b2, regB);
    // conv3 (s2): act2 -> act3 (regC)   BM=64 (WM2,WN2,MT2,NTW3), 256t, grid 512
    conv_2ph<96, 96, 32, 32, 2, 1, 2, 2, 2, 3, 256, 2><<<512, 256, 0, stream>>>(regB, wt3, b3, regC);
    // conv4: act3 -> act4 (regD)   BM=64 (WM2,WN4,MT2,NTW3), 512t -> 16 waves/CU, grid 512
    conv_2ph<96, 192, 16, 16, 1, 1, 2, 4, 2, 3, 512, 4><<<512, 512, 0, stream>>>(regC, wt4, b4, regD);
    // merged halo re-zero: act5 (regA, free after conv2) + act6 (regC, free after conv4)
    Halo4 h56;
    h56.d[0] = {regA, 18, 18, 192};
    h56.d[1] = {regC, 10, 10, 192};
    h56.n = 2; h56.cum[0] = 0;
    h56.cum[1] = chunks(18, 18, 192);
    h56.cum[2] = h56.cum[1] + chunks(10, 10, 192);
    halo_zero_multi<<<CDIV(h56.cum[2], TPB), TPB, 0, stream>>>(h56);
    // conv5: act4 -> act5 (regA)   BM=64 (WM2,WN4,MT2,NTW3), 512t, grid 512, NSTEP=54
    conv_2ph<192, 192, 16, 16, 1, 1, 2, 4, 2, 3, 512, 4><<<512, 512, 0, stream>>>(regD, wt5, b5, regA);
    // conv6 (s2): act5 -> act6 (regC)   conv_2ph BM=32 (WM2,WN4,MT1,NTW3), 512t, grid 256
    conv_2ph<192, 192, 16, 16, 2, 1, 2, 4, 1, 3, 512, 2><<<256, 512, 0, stream>>>(regA, wt6, b6, regC);
    // conv7: act6 -> act7 (regD)   conv_2ph BM=32, 512t, grid 256 (8 waves/CU vs 4)
    conv_2ph<192, 192, 8, 8, 1, 1, 2, 4, 1, 3, 512, 2><<<256, 512, 0, stream>>>(regC, wt7, b7, regD);
    // conv8 (1x1): act7 -> act8 (regB)   register-ring kernel
    conv_lds<192, 192, 8, 8, 1, 0, 1, 4, 1, 3, 6, 256, 3><<<512, 256, 0, stream>>>(regD, wt8, b8, regB);
    // conv9 (1x1 192->10): act8 -> act9 fp32
    conv9_kernel<<<128, 256, 0, stream>>>(regB, wt9, b9, act9);
    // fused fc1+fc2+encode
    head_kernel<<<BATCH, 128, 0, stream>>>(act9, fw1, fb1, fw2, fb2, p11, s11, out);
}

// Round 22
// 184.467 us; speedup vs baseline: 1.2369x; 1.0078x over previous
//
#include <hip/hip_runtime.h>
#include <hip/hip_bf16.h>

#define BATCH 128
#define CDIV(a, b) (((a) + (b) - 1) / (b))

typedef __attribute__((ext_vector_type(8))) short short8;
typedef __attribute__((ext_vector_type(4))) float f32x4;

// compile-time unroll helpers
template <int V> struct ic { static constexpr int value = V; };
template <int... I> struct iseq {};
template <int N, int... I> struct mkseq : mkseq<N - 1, N - 1, I...> {};
template <int... I> struct mkseq<0, I...> { using type = iseq<I...>; };
template <class F, int... I>
__device__ __forceinline__ void unroll_all(F&& f, iseq<I...>) { (f(ic<I>{}), ...); }

// async global->LDS 16B: LDS dest = wave-uniform base + lane*16; global source per-lane
__device__ __forceinline__ void gload_lds16(const void* g, void* l) {
    __builtin_amdgcn_global_load_lds(
        (const __attribute__((address_space(1))) void*)g,
        (__attribute__((address_space(3))) void*)l, 16, 0, 0);
}

// 16B-unit swizzle sigma(u) = u ^ ((u>>2)&7) (bank spread for stride-4-unit frag reads)
__device__ __forceinline__ int sig_u(int u) { return u ^ ((u >> 2) & 7); }
__device__ __forceinline__ int inv_sig_u(int x) {
    int r0 = ((x >> 2) ^ (x >> 4)) & 1;
    int r1 = (x >> 3) & 1;
    int r2 = (x >> 4) & 1;
    return x ^ (r0 | (r1 << 1) | (r2 << 2));
}

// ---------------- zero fill (f32) ----------------
__global__ void fill0_f32(float* __restrict__ p, int n) {
    int i = blockIdx.x * blockDim.x + threadIdx.x;
    if (i < n) p[i] = 0.0f;
}

// ---------------- decode: scatter A0 -> padded NHWC f32 [B][34][34][4] ----------------
__global__ void decode_kernel(const float* __restrict__ y, const int* __restrict__ p,
                              const float* __restrict__ s, float* __restrict__ x) {
    const int n = 3073;
    int idx = blockIdx.x * blockDim.x + threadIdx.x;
    if (idx >= BATCH * n) return;
    int i = idx % n, b = idx / n;
    int pi = p[i];
    if (pi >= 3072) return;
    float v = y[(size_t)b * n + i] / s[i];
    int c = pi >> 10; int r = pi & 1023; int h = r >> 5; int w = r & 31;
    x[((size_t)(b * 34 + h + 1) * 34 + (w + 1)) * 4 + c] = v;
}

// ---------------- fused halo zero (up to 4 padded bf16 NHWC buffers) ----------------
struct HaloDesc { __hip_bfloat16* p; int Hp, Wp, C; };
struct Halo4 { HaloDesc d[4]; int cum[5]; int n; };

__global__ void halo_zero_multi(Halo4 h) {
    int idx = blockIdx.x * 256 + threadIdx.x;
    if (idx >= h.cum[h.n]) return;
    int seg = 0;
    while (idx >= h.cum[seg + 1]) ++seg;
    int local = idx - h.cum[seg];
    HaloDesc d = h.d[seg];
    int perB = (2 * d.Wp + 2 * (d.Hp - 2)) * d.C / 8;
    int b = local / perB;
    int r = (local % perB) * 8;
    int WpC = d.Wp * d.C;
    long addr;
    if (r < WpC) {
        addr = (long)(b * d.Hp) * WpC + r;
    } else if (r < 2 * WpC) {
        addr = (long)(b * d.Hp + d.Hp - 1) * WpC + (r - WpC);
    } else {
        int r3 = r - 2 * WpC;
        int sideN = (d.Hp - 2) * d.C;
        int side = r3 / sideN;
        int r4 = r3 % sideN;
        int row = 1 + r4 / d.C, c = r4 % d.C;
        addr = ((long)(b * d.Hp + row) * d.Wp + (side ? d.Wp - 1 : 0)) * d.C + c;
    }
    *(uint4*)((char*)d.p + addr * 2) = uint4{0, 0, 0, 0};
}

// ------ fused weight transform: OIHW f32 -> [pos*KS+kk][CoutPad][32] bf16 (k-chunked) ---
struct WtSeg { const float* src; __hip_bfloat16* dst; int Cout, Cin, KK, CoutPad; };
struct Wt8 { WtSeg s[8]; int cum[9]; };

__global__ void wt_transform_multi(Wt8 w) {
    int idx = blockIdx.x * 256 + threadIdx.x;
    if (idx >= w.cum[8]) return;
    int seg = 0;
    while (idx >= w.cum[seg + 1]) ++seg;
    int local = idx - w.cum[seg];
    WtSeg sg = w.s[seg];
    int c2 = local % 32; int t = local / 32;
    int co = t % sg.CoutPad; int t2 = t / sg.CoutPad;   // t2 = pos*KS + kk
    int KS = sg.Cin / 32;
    int kk = t2 % KS; int pos = t2 / KS;
    int cin = kk * 32 + c2;
    float v = (co < sg.Cout) ? sg.src[((size_t)co * sg.Cin + cin) * sg.KK + pos] : 0.0f;
    sg.dst[local] = __float2bfloat16(v);
}

// ---------------- conv1: 3->96 @32x32, fp32, 4 threads/pixel, packed stores ------------
__global__ __launch_bounds__(256) void conv1_kernel(
    const float* __restrict__ in, const float* __restrict__ w,
    const float* __restrict__ bias, __hip_bfloat16* __restrict__ out) {
    __shared__ float ws[96 * 27];
    __shared__ float bs[96];
    for (int i = threadIdx.x; i < 96 * 27; i += 256) ws[i] = w[i];
    if (threadIdx.x < 96) bs[threadIdx.x] = bias[threadIdx.x];
    __syncthreads();
    int idx = blockIdx.x * 256 + threadIdx.x;
    int q = idx & 3; int pix = idx >> 2;
    int b = pix >> 10, r = pix & 1023, oh = r >> 5, ow = r & 31;
    const float* ib = in + ((size_t)(b * 34 + oh) * 34 + ow) * 4;
    float patch[9][3];
#pragma unroll
    for (int ph = 0; ph < 3; ++ph)
#pragma unroll
        for (int pw = 0; pw < 3; ++pw) {
            float4 v = *(const float4*)(ib + ((size_t)ph * 34 + pw) * 4);
            patch[ph * 3 + pw][0] = v.x; patch[ph * 3 + pw][1] = v.y; patch[ph * 3 + pw][2] = v.z;
        }
    const int c0 = q * 24;
    float acc[24];
#pragma unroll
    for (int j = 0; j < 24; ++j) acc[j] = bs[c0 + j];
    for (int j = 0; j < 24; ++j) {
        const float* wc = &ws[(c0 + j) * 27];
#pragma unroll
        for (int ci = 0; ci < 3; ++ci)
#pragma unroll
            for (int pos = 0; pos < 9; ++pos)
                acc[j] = fmaf(patch[pos][ci], wc[ci * 9 + pos], acc[j]);
    }
    __hip_bfloat16* ob = out + ((size_t)(b * 34 + oh + 1) * 34 + ow + 1) * 96 + c0;
#pragma unroll
    for (int g = 0; g < 3; ++g) {
        union { uint4 u; unsigned short s[8]; } pk;
#pragma unroll
        for (int e = 0; e < 8; ++e) {
            __hip_bfloat16 hv = __float2bfloat16(fmaxf(acc[g * 8 + e], 0.0f));
            pk.s[e] = *(unsigned short*)&hv;
        }
        *(uint4*)(ob + g * 8) = pk.u;
    }
}

// ======== conv_2ph: shared LDS chunk ring + counted vmcnt + RAW barrier, WMxWN waves ====
// LA=2, DEPTH=4 (race-free: DEPTH >= LA+2). 512-thread variants (8 waves) double
// waves/CU at identical LDS footprint (LDS is the binding resource, not threads).
template <int CIN, int COUT, int HIN, int WIN, int STRIDE, int R,
          int WM, int WN, int MT, int NTW, int THREADS, int MINW>
__global__ __launch_bounds__(THREADS, MINW) void conv_2ph(
    const __hip_bfloat16* __restrict__ in,   // [B][HIN+2][WIN+2][CIN]
    const __hip_bfloat16* __restrict__ wt,   // [(2R+1)^2*KS][COUT][32]
    const float* __restrict__ bias,
    __hip_bfloat16* __restrict__ out) {      // [B][HOUT+2][WOUT+2][COUT]
    constexpr int HOUT = HIN / STRIDE, WOUT = WIN / STRIDE;
    constexpr int Hp = HIN + 2, Wp = WIN + 2;
    constexpr int Hpo = HOUT + 2, Wpo = WOUT + 2;
    constexpr int D = 2 * R + 1;
    constexpr int KS = CIN / 32;
    constexpr int NSTEP = D * D * KS;
    constexpr int WAVES = THREADS / 64;
    static_assert(WAVES == WM * WN, "wave grid");
    constexpr int BMPIX = WM * MT * 16;
    static_assert(WN * NTW * 16 == COUT, "N covers COUT");
    constexpr int AUN = BMPIX * 4;           // A 16B-units per chunk
    constexpr int BUN = COUT * 4;            // B 16B-units per chunk
    constexpr int CUN = AUN + BUN;
    constexpr int DEPTH = 4, LA = 2;         // DEPTH >= LA+2 (race-free ring)
    constexpr int LPW = CDIV(CUN, 64 * WAVES);
    constexpr int CUN_ALLOC = LPW * 64 * WAVES;   // incl. scratch tail for dummy loads

    __shared__ short8 lds[DEPTH * CUN_ALLOC];

    int wid = threadIdx.x >> 6;
    int lane = threadIdx.x & 63;
    int col = lane & 15, kgrp = lane >> 4;
    int wm = wid / WN, wn = wid % WN;
    int n0 = wn * (NTW * 16);
    int mBase = wm * (MT * 16);

    // ---- per-lane stage descriptors (source pre-inverse-swizzled) ----
    const __hip_bfloat16* aSrc[LPW];
    int bOff[LPW];
    bool isA[LPW];
#pragma unroll
    for (int i = 0; i < LPW; ++i) {
        int x = (wid * LPW + i) * 64 + lane;     // LDS unit within (padded) chunk
        if (x < AUN) {
            isA[i] = true;
            int v = inv_sig_u(x);
            int p = v >> 2, q = v & 3;
            int gp = blockIdx.x * BMPIX + p;
            int b = gp / (HOUT * WOUT);
            int r = gp % (HOUT * WOUT);
            int oh = r / WOUT, ow = r % WOUT;
            aSrc[i] = in + ((size_t)(b * Hp + oh * STRIDE + 1 - R) * Wp
                            + ow * STRIDE + 1 - R) * CIN + q * 8;
            bOff[i] = 0;
        } else {
            isA[i] = false;
            // units in [AUN, CUN): real B; units >= CUN: dummy (read chunk start)
            bOff[i] = (x < CUN) ? inv_sig_u(x - AUN) * 8 : 0;
            aSrc[i] = in;
        }
    }
    // ---- frag read offsets (swizzled, within chunk) ----
    int aRd[MT], bRd[NTW];
#pragma unroll
    for (int mt = 0; mt < MT; ++mt)
        aRd[mt] = sig_u((mBase + mt * 16 + col) * 4 + kgrp);
#pragma unroll
    for (int nt = 0; nt < NTW; ++nt)
        bRd[nt] = AUN + sig_u((n0 + nt * 16 + col) * 4 + kgrp);

    auto stepAoff = [](int s) {
        int pos = s / KS, kk = s - (s / KS) * KS;
        return ((pos / D) * Wp + (pos % D)) * CIN + kk * 32;
    };
    auto stage = [&](int s) {
        int slot = s % DEPTH;
        int aoff = stepAoff(s);
        const __hip_bfloat16* wchunk = wt + (size_t)s * (COUT * 32);
#pragma unroll
        for (int i = 0; i < LPW; ++i) {
            const __hip_bfloat16* src = isA[i] ? (aSrc[i] + aoff) : (wchunk + bOff[i]);
            gload_lds16(src, &lds[slot * CUN_ALLOC + (wid * LPW + i) * 64]);
        }
    };

    f32x4 acc[MT][NTW] = {};
    stage(0);
    if constexpr (1 < NSTEP) stage(1);

    unroll_all([&](auto sc) {
        constexpr int s = decltype(sc)::value;
        if constexpr (s + LA < NSTEP) stage(s + LA);
        constexpr int C = (s + 1 < NSTEP ? 1 : 0) + (s + 2 < NSTEP ? 1 : 0);
        asm volatile("s_waitcnt vmcnt(%0)" :: "i"(C * LPW) : "memory");
        __builtin_amdgcn_s_barrier();            // raw rendezvous, no drain
        __builtin_amdgcn_sched_barrier(0);
        constexpr int slot = s % DEPTH;
        short8 af[MT], bfr[NTW];
#pragma unroll
        for (int mt = 0; mt < MT; ++mt) af[mt] = lds[slot * CUN_ALLOC + aRd[mt]];
#pragma unroll
        for (int nt = 0; nt < NTW; ++nt) bfr[nt] = lds[slot * CUN_ALLOC + bRd[nt]];
#pragma unroll
        for (int nt = 0; nt < NTW; ++nt)
#pragma unroll
            for (int mt = 0; mt < MT; ++mt)
                acc[mt][nt] = __builtin_amdgcn_mfma_f32_16x16x32_bf16(
                    af[mt], bfr[nt], acc[mt][nt], 0, 0, 0);
    }, typename mkseq<NSTEP>::type{});

    // epilogue: bias + relu + bf16 store into padded NHWC
#pragma unroll
    for (int mt = 0; mt < MT; ++mt) {
#pragma unroll
        for (int nt = 0; nt < NTW; ++nt) {
            int cout = n0 + nt * 16 + col;
            float bv = bias[cout];
#pragma unroll
            for (int rg = 0; rg < 4; ++rg) {
                int p = mBase + mt * 16 + kgrp * 4 + rg;
                int gp = blockIdx.x * BMPIX + p;
                int b = gp / (HOUT * WOUT);
                int r = gp % (HOUT * WOUT);
                int oh = r / WOUT, ow = r % WOUT;
                float v = fmaxf(acc[mt][nt][rg] + bv, 0.0f);
                out[((size_t)(b * Hpo + oh + 1) * Wpo + ow + 1) * COUT + cout] =
                    __float2bfloat16(v);
            }
        }
    }
}

// ---------------- conv9: 1x1 192->10 (pad16), relu, fp32 NCHW-flat out [B][640] --------
__global__ __launch_bounds__(256) void conv9_kernel(
    const __hip_bfloat16* __restrict__ in, const __hip_bfloat16* __restrict__ wt,
    const float* __restrict__ bias, float* __restrict__ out) {
    int wid = threadIdx.x >> 6;
    int lane = threadIdx.x & 63;
    int wave = blockIdx.x * 4 + wid;
    int m0 = wave * 16;
    int col = lane & 15;
    int kgrp = lane >> 4;
    int m = m0 + col;
    int b = m >> 6; int r = m & 63; int oh = r >> 3; int ow = r & 7;
    const __hip_bfloat16* abase = in + ((size_t)(b * 10 + oh + 1) * 10 + ow + 1) * 192 + kgrp * 8;
    f32x4 acc = {};
#pragma unroll
    for (int kk = 0; kk < 6; ++kk) {
        short8 bfr = *reinterpret_cast<const short8*>(wt + ((size_t)kk * 16 + col) * 32 + kgrp * 8);
        short8 a = *reinterpret_cast<const short8*>(abase + kk * 32);
        acc = __builtin_amdgcn_mfma_f32_16x16x32_bf16(a, bfr, acc, 0, 0, 0);
    }
    if (col < 10) {
        float bv = bias[col];
#pragma unroll
        for (int rg = 0; rg < 4; ++rg) {
            int m2 = m0 + kgrp * 4 + rg;
            int b2 = m2 >> 6; int r2 = m2 & 63;
            out[(size_t)b2 * 640 + col * 64 + r2] = fmaxf(acc[rg] + bv, 0.0f);
        }
    }
}

// ---------------- fused head: fc1(640->100)+relu, fc2(100->10), encode -----------------
__global__ __launch_bounds__(128) void head_kernel(
    const float* __restrict__ act9, const float* __restrict__ fw1, const float* __restrict__ fb1,
    const float* __restrict__ fw2, const float* __restrict__ fb2,
    const int* __restrict__ p11, const float* __restrict__ s11, float* __restrict__ out) {
    __shared__ float x[640];
    __shared__ float h[100];
    __shared__ float o[10];
    int b = blockIdx.x, t = threadIdx.x;
    for (int i = t; i < 160; i += 128)
        ((float4*)x)[i] = ((const float4*)(act9 + (size_t)b * 640))[i];
    __syncthreads();
    if (t < 100) {
        float acc = fb1[t];
        const float4* wr = (const float4*)(fw1 + (size_t)t * 640);
        const float4* xv = (const float4*)x;
#pragma unroll 4
        for (int i = 0; i < 160; ++i) {
            float4 wv = wr[i], qv = xv[i];
            acc = fmaf(wv.x, qv.x, acc); acc = fmaf(wv.y, qv.y, acc);
            acc = fmaf(wv.z, qv.z, acc); acc = fmaf(wv.w, qv.w, acc);
        }
        h[t] = fmaxf(acc, 0.0f);
    }
    __syncthreads();
    if (t < 10) {
        float acc = fb2[t];
        for (int i = 0; i < 100; ++i) acc = fmaf(h[i], fw2[t * 100 + i], acc);
        o[t] = acc;
    }
    __syncthreads();
    if (t < 11) {
        int pi = p11[t];
        out[(size_t)b * 11 + t] = s11[t] * (pi == 10 ? 1.0f : o[pi]);
    }
}

extern "C" void kernel_launch(void* const* d_in, const int* in_sizes, int n_in,
                              void* d_out, int out_size, void* d_ws, size_t ws_size,
                              hipStream_t stream) {
    const int*   p0  = (const int*)  d_in[0];
    const float* s0  = (const float*)d_in[1];
    const int*   p11 = (const int*)  d_in[26];
    const float* s11 = (const float*)d_in[27];
    const float* w1 = (const float*)d_in[28]; const float* b1 = (const float*)d_in[29];
    const float* w2 = (const float*)d_in[30]; const float* b2 = (const float*)d_in[31];
    const float* w3 = (const float*)d_in[32]; const float* b3 = (const float*)d_in[33];
    const float* w4 = (const float*)d_in[34]; const float* b4 = (const float*)d_in[35];
    const float* w5 = (const float*)d_in[36]; const float* b5 = (const float*)d_in[37];
    const float* w6 = (const float*)d_in[38]; const float* b6 = (const float*)d_in[39];
    const float* w7 = (const float*)d_in[40]; const float* b7 = (const float*)d_in[41];
    const float* w8 = (const float*)d_in[42]; const float* b8 = (const float*)d_in[43];
    const float* w9 = (const float*)d_in[44]; const float* b9 = (const float*)d_in[45];
    const float* fw1 = (const float*)d_in[46]; const float* fb1 = (const float*)d_in[47];
    const float* fw2 = (const float*)d_in[48]; const float* fb2 = (const float*)d_in[49];
    const float* A0 = (const float*)d_in[50];
    float* out = (float*)d_out;

    // ---- workspace carve-up (256B aligned) ----
    size_t off = 0;
    auto alloc = [&](size_t bytes) {
        void* p = (char*)d_ws + off;
        off += (bytes + 255) & ~(size_t)255;
        return p;
    };
    const size_t SZ_3434_96  = (size_t)BATCH * 34 * 34 * 96 * 2;
    const size_t SZ_1818_96  = (size_t)BATCH * 18 * 18 * 96 * 2;
    const size_t SZ_1818_192 = (size_t)BATCH * 18 * 18 * 192 * 2;

    float* dec = (float*)alloc((size_t)BATCH * 34 * 34 * 4 * 4);
    __hip_bfloat16* regA = (__hip_bfloat16*)alloc(SZ_3434_96);   // act1; act5 [18,18,192]
    __hip_bfloat16* regB = (__hip_bfloat16*)alloc(SZ_3434_96);   // act2; act8 [10,10,192]
    __hip_bfloat16* regC = (__hip_bfloat16*)alloc(SZ_1818_96);   // act3; act6 [10,10,192]
    __hip_bfloat16* regD = (__hip_bfloat16*)alloc(SZ_1818_192);  // act4; act7 [10,10,192]
    __hip_bfloat16* wt2 = (__hip_bfloat16*)alloc((size_t)9 * 96 * 96 * 2);
    __hip_bfloat16* wt3 = (__hip_bfloat16*)alloc((size_t)9 * 96 * 96 * 2);
    __hip_bfloat16* wt4 = (__hip_bfloat16*)alloc((size_t)9 * 192 * 96 * 2);
    __hip_bfloat16* wt5 = (__hip_bfloat16*)alloc((size_t)9 * 192 * 192 * 2);
    __hip_bfloat16* wt6 = (__hip_bfloat16*)alloc((size_t)9 * 192 * 192 * 2);
    __hip_bfloat16* wt7 = (__hip_bfloat16*)alloc((size_t)9 * 192 * 192 * 2);
    __hip_bfloat16* wt8 = (__hip_bfloat16*)alloc((size_t)1 * 192 * 192 * 2);
    __hip_bfloat16* wt9 = (__hip_bfloat16*)alloc((size_t)16 * 192 * 2);
    float* act9 = (float*)alloc((size_t)BATCH * 640 * 4);

    const int TPB = 256;

    // decode input
    int decN = BATCH * 34 * 34 * 4;
    fill0_f32<<<CDIV(decN, TPB), TPB, 0, stream>>>(dec, decN);
    decode_kernel<<<CDIV(BATCH * 3073, TPB), TPB, 0, stream>>>(A0, p0, s0, dec);

    // fused weight transform (k-chunk-contiguous layout)
    Wt8 wts;
    wts.s[0] = {w2, wt2, 96, 96, 9, 96};
    wts.s[1] = {w3, wt3, 96, 96, 9, 96};
    wts.s[2] = {w4, wt4, 192, 96, 9, 192};
    wts.s[3] = {w5, wt5, 192, 192, 9, 192};
    wts.s[4] = {w6, wt6, 192, 192, 9, 192};
    wts.s[5] = {w7, wt7, 192, 192, 9, 192};
    wts.s[6] = {w8, wt8, 192, 192, 1, 192};
    wts.s[7] = {w9, wt9, 10, 192, 1, 16};
    wts.cum[0] = 0;
    for (int i = 0; i < 8; ++i)
        wts.cum[i + 1] = wts.cum[i] + wts.s[i].KK * wts.s[i].CoutPad * wts.s[i].Cin;
    wt_transform_multi<<<CDIV(wts.cum[8], TPB), TPB, 0, stream>>>(wts);

    // fused halo zero: act1, act2, act3, act4
    auto chunks = [](int Hp, int Wp, int C) { return BATCH * (2 * Wp + 2 * (Hp - 2)) * C / 8; };
    Halo4 h0;
    h0.d[0] = {regA, 34, 34, 96};
    h0.d[1] = {regB, 34, 34, 96};
    h0.d[2] = {regC, 18, 18, 96};
    h0.d[3] = {regD, 18, 18, 192};
    h0.n = 4; h0.cum[0] = 0;
    for (int i = 0; i < 4; ++i)
        h0.cum[i + 1] = h0.cum[i] + chunks(h0.d[i].Hp, h0.d[i].Wp, h0.d[i].C);
    halo_zero_multi<<<CDIV(h0.cum[4], TPB), TPB, 0, stream>>>(h0);

    // conv1: dec -> act1 (regA)
    conv1_kernel<<<2048, 256, 0, stream>>>(dec, w1, b1, regA);
    // conv2: act1 -> act2 (regB)   BM=128 (WM4,WN2,MT2,NTW3), 512t -> 16 waves/CU, grid 1024
    conv_2ph<96, 96, 32, 32, 1, 1, 4, 2, 2, 3, 512, 4><<<1024, 512, 0, stream>>>(regA, wt2, b2, regB);
    // conv3 (s2): act2 -> act3 (regC)   BM=64 (WM2,WN2,MT2,NTW3), 256t, grid 512
    conv_2ph<96, 96, 32, 32, 2, 1, 2, 2, 2, 3, 256, 2><<<512, 256, 0, stream>>>(regB, wt3, b3, regC);
    // conv4: act3 -> act4 (regD)   BM=64 (WM2,WN4,MT2,NTW3), 512t -> 16 waves/CU, grid 512
    conv_2ph<96, 192, 16, 16, 1, 1, 2, 4, 2, 3, 512, 4><<<512, 512, 0, stream>>>(regC, wt4, b4, regD);
    // merged halo re-zero: act5 (regA, free after conv2) + act6 (regC, free after conv4)
    Halo4 h56;
    h56.d[0] = {regA, 18, 18, 192};
    h56.d[1] = {regC, 10, 10, 192};
    h56.n = 2; h56.cum[0] = 0;
    h56.cum[1] = chunks(18, 18, 192);
    h56.cum[2] = h56.cum[1] + chunks(10, 10, 192);
    halo_zero_multi<<<CDIV(h56.cum[2], TPB), TPB, 0, stream>>>(h56);
    // conv5: act4 -> act5 (regA)   BM=64 (WM2,WN4,MT2,NTW3), 512t, grid 512, NSTEP=54
    conv_2ph<192, 192, 16, 16, 1, 1, 2, 4, 2, 3, 512, 4><<<512, 512, 0, stream>>>(regD, wt5, b5, regA);
    // conv6 (s2): act5 -> act6 (regC)   conv_2ph BM=32 (WM2,WN4,MT1,NTW3), 512t, grid 256
    conv_2ph<192, 192, 16, 16, 2, 1, 2, 4, 1, 3, 512, 2><<<256, 512, 0, stream>>>(regA, wt6, b6, regC);
    // conv7: act6 -> act7 (regD)   conv_2ph BM=32, 512t, grid 256
    conv_2ph<192, 192, 8, 8, 1, 1, 2, 4, 1, 3, 512, 2><<<256, 512, 0, stream>>>(regC, wt7, b7, regD);
    // conv8 (1x1): act7 -> act8 (regB)   conv_2ph BM=32, 512t, grid 256, NSTEP=6
    conv_2ph<192, 192, 8, 8, 1, 0, 2, 4, 1, 3, 512, 2><<<256, 512, 0, stream>>>(regD, wt8, b8, regB);
    // conv9 (1x1 192->10): act8 -> act9 fp32
    conv9_kernel<<<128, 256, 0, stream>>>(regB, wt9, b9, act9);
    // fused fc1+fc2+encode
    head_kernel<<<BATCH, 128, 0, stream>>>(act9, fw1, fb1, fw2, fb2, p11, s11, out);
}